// Round 2
// baseline (534.320 us; speedup 1.0000x reference)
//
#include <hip/hip_runtime.h>
#include <hip/hip_bf16.h>

// Problem constants: B=2, T=2048, D=1024, H=16, G=4, K=64, F=4096
#define EPSF 1e-6f
constexpr int Bsz  = 2;
constexpr int Tseq = 2048;
constexpr int Dmod = 1024;
constexpr int Hh   = 16;
constexpr int Gg   = 4;
constexpr int Ff   = 4096;
constexpr int Mrows = Bsz * Tseq;          // 4096 tokens

typedef __attribute__((ext_vector_type(8))) short bf16x8;   // 8 bf16 (4 VGPRs)
typedef __attribute__((ext_vector_type(4))) float f32x4;
typedef __attribute__((ext_vector_type(16))) float f32x16;
typedef unsigned short u16;

// RNE fp32 -> bf16 (bit pattern as u16)
__device__ inline u16 f2bf(float x) {
    union { float f; unsigned u; } v; v.f = x;
    unsigned r = v.u + 0x7fff + ((v.u >> 16) & 1);
    return (u16)(r >> 16);
}
__device__ inline float bf2f(u16 h) {
    union { unsigned u; float f; } v; v.u = ((unsigned)h) << 16; return v.f;
}

// Async global->LDS DMA, 16 B per lane (wave-uniform base + lane*16).
__device__ __forceinline__ void async_copy16(const u16* g, u16* l) {
    __builtin_amdgcn_global_load_lds(
        (const __attribute__((address_space(1))) void*)g,
        (__attribute__((address_space(3))) void*)l, 16, 0, 0);
}

// Bank-swizzle: LDS tiles [row][32] bf16 (64 B rows). Logical k-chunk q of row
// R stored at chunk q ^ ((R>>1)&3); staging fetches global chunk
// (lane&3)^((row>>1)&3) into linear dest lane*16; reads XOR the same term.
// -> verified conflict-free (r7/r10: SQ_LDS_BANK_CONFLICT = 0).

// ---------------------------------------------------------------------------
// ALL weight prep in ONE launch (kept from r9 — sound). 14848 blocks.
// ---------------------------------------------------------------------------
__global__ __launch_bounds__(256) void wprep_all_kernel(
    const float* __restrict__ q_w, const float* __restrict__ k_w,
    const float* __restrict__ v_w, const float* __restrict__ o_w,
    const float* __restrict__ gate_w, const float* __restrict__ up_w,
    const float* __restrict__ down_w,
    u16* __restrict__ QKVT, u16* __restrict__ OTh, u16* __restrict__ OTl,
    u16* __restrict__ GTh, u16* __restrict__ UTh, u16* __restrict__ DTh)
{
    const int bx = blockIdx.x;
    const float* W; u16* Th; u16* Tl = nullptr;
    int N, Kd, ntile, ktile, drow;
    if (bx < 1024) {
        W = q_w; N = 1024; Kd = 1024; ntile = bx & 31; ktile = bx >> 5;
        Th = QKVT; drow = ntile * 32;
    } else if (bx < 1280) {
        const int i = bx - 1024;
        W = k_w; N = 256; Kd = 1024; ntile = i & 7; ktile = i >> 3;
        Th = QKVT; drow = 1024 + ntile * 32;
    } else if (bx < 1536) {
        const int i = bx - 1280;
        W = v_w; N = 256; Kd = 1024; ntile = i & 7; ktile = i >> 3;
        Th = QKVT; drow = 1280 + ntile * 32;
    } else if (bx < 2560) {
        const int i = bx - 1536;
        W = o_w; N = 1024; Kd = 1024; ntile = i & 31; ktile = i >> 5;
        Th = OTh; Tl = OTl; drow = ntile * 32;
    } else if (bx < 6656) {
        const int i = bx - 2560;
        W = gate_w; N = 4096; Kd = 1024; ntile = i & 127; ktile = i >> 7;
        Th = GTh; drow = ntile * 32;
    } else if (bx < 10752) {
        const int i = bx - 6656;
        W = up_w; N = 4096; Kd = 1024; ntile = i & 127; ktile = i >> 7;
        Th = UTh; drow = ntile * 32;
    } else {
        const int i = bx - 10752;
        W = down_w; N = 1024; Kd = 4096; ntile = i & 31; ktile = i >> 5;
        Th = DTh; drow = ntile * 32;
    }
    const int n0 = ntile * 32, k0 = ktile * 32;

    __shared__ float tile[32][33];
    const int r = threadIdx.x >> 3, c4 = (threadIdx.x & 7) * 4;
    const float4 v = *reinterpret_cast<const float4*>(&W[(size_t)(k0 + r) * N + n0 + c4]);
    tile[r][c4 + 0] = v.x; tile[r][c4 + 1] = v.y;
    tile[r][c4 + 2] = v.z; tile[r][c4 + 3] = v.w;
    __syncthreads();
    const int nl = threadIdx.x >> 3, kq = (threadIdx.x & 7) * 4;
    float x0 = tile[kq + 0][nl], x1 = tile[kq + 1][nl];
    float x2 = tile[kq + 2][nl], x3 = tile[kq + 3][nl];
    ushort4 h;
    h.x = f2bf(x0); h.y = f2bf(x1); h.z = f2bf(x2); h.w = f2bf(x3);
    *reinterpret_cast<ushort4*>(&Th[(size_t)(drow + nl) * Kd + k0 + kq]) = h;
    if (Tl) {
        ushort4 l;
        l.x = f2bf(x0 - bf2f(h.x)); l.y = f2bf(x1 - bf2f(h.y));
        l.z = f2bf(x2 - bf2f(h.z)); l.w = f2bf(x3 - bf2f(h.w));
        *reinterpret_cast<ushort4*>(&Tl[(size_t)(drow + nl) * Kd + k0 + kq]) = l;
    }
}

// ---------------------------------------------------------------------------
// RMSNorm over D=1024 -> bf16 hi (+ optional lo). One block per token.
// ---------------------------------------------------------------------------
template <int LO>
__global__ __launch_bounds__(256) void rmsnorm_split_kernel(
    const float* __restrict__ x, const float* __restrict__ scale,
    u16* __restrict__ oh, u16* __restrict__ ol)
{
    const int row = blockIdx.x;
    const int tid = threadIdx.x;
    const float4 v = reinterpret_cast<const float4*>(x + (size_t)row * Dmod)[tid];
    float ss = v.x * v.x + v.y * v.y + v.z * v.z + v.w * v.w;
    #pragma unroll
    for (int off = 32; off; off >>= 1) ss += __shfl_xor(ss, off, 64);
    __shared__ float part[4];
    if ((tid & 63) == 0) part[tid >> 6] = ss;
    __syncthreads();
    const float tot = part[0] + part[1] + part[2] + part[3];
    const float rstd = rsqrtf(tot * (1.0f / Dmod) + EPSF);
    const float4 sc = reinterpret_cast<const float4*>(scale)[tid];
    float o0 = v.x * rstd * sc.x, o1 = v.y * rstd * sc.y;
    float o2 = v.z * rstd * sc.z, o3 = v.w * rstd * sc.w;
    ushort4 h;
    h.x = f2bf(o0); h.y = f2bf(o1); h.z = f2bf(o2); h.w = f2bf(o3);
    *reinterpret_cast<ushort4*>(&oh[(size_t)row * Dmod + tid * 4]) = h;
    if (LO) {
        ushort4 l;
        l.x = f2bf(o0 - bf2f(h.x)); l.y = f2bf(o1 - bf2f(h.y));
        l.z = f2bf(o2 - bf2f(h.z)); l.w = f2bf(o3 - bf2f(h.w));
        *reinterpret_cast<ushort4*>(&ol[(size_t)row * Dmod + tid * 4]) = l;
    }
}

// ---------------------------------------------------------------------------
// Split-bf16 MFMA GEMM, async DMA + swizzle (unchanged from r7).
// ---------------------------------------------------------------------------
template <int ASPLIT, int BSPLIT, int RES>
__global__ __launch_bounds__(256, 2) void mfma_gemm_kernel(
    const u16* __restrict__ Ah, const u16* __restrict__ Al,
    const u16* __restrict__ Bh, const u16* __restrict__ Bl,
    const float* __restrict__ res, float* __restrict__ C,
    int M, int N, int Kd)
{
    __shared__ u16 As_h[128 * 32];
    __shared__ u16 As_l[128 * 32];
    __shared__ u16 Bs_h[128 * 32];
    __shared__ u16 Bs_l[128 * 32];

    const int tid = threadIdx.x;
    const int lane = tid & 63, wave = tid >> 6;
    const int wm = (wave >> 1) * 64, wn = (wave & 1) * 64;
    const int m0 = blockIdx.y * 128, n0 = blockIdx.x * 128;
    const int fm = lane & 15, quad = lane >> 4;
    const int fsw = (fm >> 1) & 3;
    const int fcol = ((quad ^ fsw) * 8);

    f32x4 acc[4][4];
    #pragma unroll
    for (int i = 0; i < 4; ++i)
        #pragma unroll
        for (int j = 0; j < 4; ++j) acc[i][j] = (f32x4){0.f, 0.f, 0.f, 0.f};

    const int lrow = lane >> 2;
    const int lchunk = lane & 3;
    const int schunk = lchunk ^ ((lrow >> 1) & 3);

    for (int k0 = 0; k0 < Kd; k0 += 32) {
        __syncthreads();
        #pragma unroll
        for (int p = 0; p < 2; ++p) {
            const int row = wave * 32 + p * 16 + lrow;
            const size_t ga = (size_t)(m0 + row) * Kd + k0 + schunk * 8;
            const size_t gb = (size_t)(n0 + row) * Kd + k0 + schunk * 8;
            const int ls = row * 32 + lchunk * 8;
            async_copy16(&Ah[ga], &As_h[ls]);
            if (ASPLIT) async_copy16(&Al[ga], &As_l[ls]);
            async_copy16(&Bh[gb], &Bs_h[ls]);
            if (BSPLIT) async_copy16(&Bl[gb], &Bs_l[ls]);
        }
        __syncthreads();

        bf16x8 ah[4], al[4], bh[4], bl[4];
        #pragma unroll
        for (int t = 0; t < 4; ++t) {
            const int ra = (wm + t * 16 + fm) * 32 + fcol;
            const int rb = (wn + t * 16 + fm) * 32 + fcol;
            ah[t] = *reinterpret_cast<const bf16x8*>(&As_h[ra]);
            bh[t] = *reinterpret_cast<const bf16x8*>(&Bs_h[rb]);
            if (ASPLIT) al[t] = *reinterpret_cast<const bf16x8*>(&As_l[ra]);
            if (BSPLIT) bl[t] = *reinterpret_cast<const bf16x8*>(&Bs_l[rb]);
        }
        #pragma unroll
        for (int mt = 0; mt < 4; ++mt)
            #pragma unroll
            for (int nt = 0; nt < 4; ++nt) {
                acc[mt][nt] = __builtin_amdgcn_mfma_f32_16x16x32_bf16(
                    ah[mt], bh[nt], acc[mt][nt], 0, 0, 0);
                if (BSPLIT)
                    acc[mt][nt] = __builtin_amdgcn_mfma_f32_16x16x32_bf16(
                        ah[mt], bl[nt], acc[mt][nt], 0, 0, 0);
                if (ASPLIT)
                    acc[mt][nt] = __builtin_amdgcn_mfma_f32_16x16x32_bf16(
                        al[mt], bh[nt], acc[mt][nt], 0, 0, 0);
            }
    }

    const int cr = (lane >> 4) * 4, cn = lane & 15;
    #pragma unroll
    for (int mt = 0; mt < 4; ++mt)
        #pragma unroll
        for (int nt = 0; nt < 4; ++nt)
            #pragma unroll
            for (int r = 0; r < 4; ++r) {
                const int gm = m0 + wm + mt * 16 + cr + r;
                const int gn = n0 + wn + nt * 16 + cn;
                float v = acc[mt][nt][r];
                if (RES) v += res[(size_t)gm * N + gn];
                C[(size_t)gm * N + gn] = v;
            }
}

// ---------------------------------------------------------------------------
// Fused QKV GEMM + qk-norm + RoPE + bf16 split epilogue; V stored TRANSPOSED
// directly (kept from r9 — sound).
// ---------------------------------------------------------------------------
__global__ __launch_bounds__(256, 2) void qkv_fused_kernel(
    const u16* __restrict__ Ah, const u16* __restrict__ Bh,
    const float* __restrict__ qn, const float* __restrict__ kn,
    const float* __restrict__ sinp, const float* __restrict__ cosp,
    u16* __restrict__ Qbh, u16* __restrict__ Qbl,
    u16* __restrict__ Kbh, u16* __restrict__ Kbl,
    u16* __restrict__ Vth, u16* __restrict__ Vtl)
{
    __shared__ u16 As_h[128 * 32];
    __shared__ u16 Bs_h[128 * 32];

    const int Kd = 1024;
    const int tid = threadIdx.x;
    const int lane = tid & 63, wave = tid >> 6;
    const int wm = (wave >> 1) * 64, wn = (wave & 1) * 64;
    const int m0 = blockIdx.y * 128, n0 = blockIdx.x * 128;
    const int fm = lane & 15, quad = lane >> 4;
    const int fsw = (fm >> 1) & 3;
    const int fcol = ((quad ^ fsw) * 8);

    f32x4 acc[4][4];
    #pragma unroll
    for (int i = 0; i < 4; ++i)
        #pragma unroll
        for (int j = 0; j < 4; ++j) acc[i][j] = (f32x4){0.f, 0.f, 0.f, 0.f};

    const int lrow = lane >> 2;
    const int lchunk = lane & 3;
    const int schunk = lchunk ^ ((lrow >> 1) & 3);

    for (int k0 = 0; k0 < Kd; k0 += 32) {
        __syncthreads();
        #pragma unroll
        for (int p = 0; p < 2; ++p) {
            const int row = wave * 32 + p * 16 + lrow;
            const size_t ga = (size_t)(m0 + row) * Kd + k0 + schunk * 8;
            const size_t gb = (size_t)(n0 + row) * Kd + k0 + schunk * 8;
            const int ls = row * 32 + lchunk * 8;
            async_copy16(&Ah[ga], &As_h[ls]);
            async_copy16(&Bh[gb], &Bs_h[ls]);
        }
        __syncthreads();

        bf16x8 ah[4], bh[4];
        #pragma unroll
        for (int t = 0; t < 4; ++t) {
            ah[t] = *reinterpret_cast<const bf16x8*>(&As_h[(wm + t * 16 + fm) * 32 + fcol]);
            bh[t] = *reinterpret_cast<const bf16x8*>(&Bs_h[(wn + t * 16 + fm) * 32 + fcol]);
        }
        #pragma unroll
        for (int mt = 0; mt < 4; ++mt)
            #pragma unroll
            for (int nt = 0; nt < 4; ++nt)
                acc[mt][nt] = __builtin_amdgcn_mfma_f32_16x16x32_bf16(
                    ah[mt], bh[nt], acc[mt][nt], 0, 0, 0);
    }

    const int gn0 = n0 + wn;          // wave col base, 64-aligned
    const int l15 = lane & 15;

    if (gn0 < 1280) {
        // ---- Q or K: per-head RMSNorm + RoPE + split ----
        const bool isQ = (gn0 < 1024);
        const float* nsc = isQ ? qn : kn;
        const float osc = isQ ? 0.125f : 1.0f;
        u16* __restrict__ oh = isQ ? Qbh : Kbh;
        u16* __restrict__ ol = isQ ? Qbl : Kbl;
        const int rowstride = isQ ? 1024 : 256;
        const int colbase = isQ ? gn0 : gn0 - 1024;
        float sc[4];
        #pragma unroll
        for (int nt = 0; nt < 4; ++nt) sc[nt] = nsc[nt * 16 + l15];

        #pragma unroll
        for (int mt = 0; mt < 4; ++mt)
            #pragma unroll
            for (int r = 0; r < 4; ++r) {
                const int bt = m0 + wm + mt * 16 + quad * 4 + r;
                float v[4];
                #pragma unroll
                for (int nt = 0; nt < 4; ++nt) v[nt] = acc[mt][nt][r];
                float ss = v[0] * v[0] + v[1] * v[1] + v[2] * v[2] + v[3] * v[3];
                #pragma unroll
                for (int off = 1; off < 16; off <<= 1)
                    ss += __shfl_xor(ss, off, 16);
                const float rstd = rsqrtf(ss * (1.0f / 64.0f) + EPSF);
                float nv[4];
                #pragma unroll
                for (int nt = 0; nt < 4; ++nt) nv[nt] = v[nt] * rstd * sc[nt];
                const float s0 = sinp[bt * 32 + l15];
                const float c0 = cosp[bt * 32 + l15];
                const float s1 = sinp[bt * 32 + 16 + l15];
                const float c1 = cosp[bt * 32 + 16 + l15];
                float o[4];
                o[0] = (nv[0] * c0 - nv[2] * s0) * osc;
                o[1] = (nv[1] * c1 - nv[3] * s1) * osc;
                o[2] = (nv[2] * c0 + nv[0] * s0) * osc;
                o[3] = (nv[3] * c1 + nv[1] * s1) * osc;
                #pragma unroll
                for (int nt = 0; nt < 4; ++nt) {
                    const size_t off = (size_t)bt * rowstride + colbase + nt * 16 + l15;
                    const u16 hi = f2bf(o[nt]);
                    oh[off] = hi;
                    ol[off] = f2bf(o[nt] - bf2f(hi));
                }
            }
    } else {
        // ---- V: bf16 split, stored transposed: Vt[(b*4+g)*64+d][t] ----
        const int g = (gn0 - 1280) >> 6;
        const int b = (m0 + wm) >> 11;
        const int tb = ((m0 + wm) & 2047) + quad * 4;
        #pragma unroll
        for (int mt = 0; mt < 4; ++mt)
            #pragma unroll
            for (int nt = 0; nt < 4; ++nt) {
                const float v0 = acc[mt][nt][0], v1 = acc[mt][nt][1];
                const float v2 = acc[mt][nt][2], v3 = acc[mt][nt][3];
                ushort4 hv, lv;
                hv.x = f2bf(v0); hv.y = f2bf(v1); hv.z = f2bf(v2); hv.w = f2bf(v3);
                lv.x = f2bf(v0 - bf2f(hv.x)); lv.y = f2bf(v1 - bf2f(hv.y));
                lv.z = f2bf(v2 - bf2f(hv.z)); lv.w = f2bf(v3 - bf2f(hv.w));
                const size_t off =
                    ((size_t)((b * 4 + g) * 64 + nt * 16 + l15)) * Tseq + tb + mt * 16;
                *reinterpret_cast<ushort4*>(&Vth[off]) = hv;
                *reinterpret_cast<ushort4*>(&Vtl[off]) = lv;
            }
    }
}

// ---------------------------------------------------------------------------
// Fused gate/up GEMM, r11: 256x128 tile, 512 threads (8 waves, 2Mx4N), on
// v_mfma_f32_32x32x16_bf16 (2x fewer matrix instrs, 4060 vs 3378 FLOP/cyc/CU),
// TWO phases per K-step (hi, lo — 16 MFMA each; halves barrier count vs r10),
// triple-buffered LDS with UNROLL-3 (all buffer indices compile-time), counted
// vmcnt(6) (never drained in the main loop), setprio around MFMA clusters.
// Same chunk-XOR bank swizzle (conflict-free r7/r10). Per-output accumulation
// order preserved: hi contribution then lo contribution per K-step (within-K
// grouping 32->16+16 changes fp32 rounding by O(ulp) only).
//
// Race-safety invariants (triple buffer, stage t+2 during step t):
//  * stage(t+2) targets buf[(t+2)%3] = buf[(t-1)%3]; its last reads completed
//    before step t-1's closing barrier (lgkmcnt(0) precedes it).
//  * reads of buf[t%3] gated by vmcnt(6) at end of step t-1: outstanding then
//    = t's 6 loads (older) + t+1's (younger); vmcnt(6) completes t's (FIFO,
//    m135).
// Fragment layouts (32x32x16): A: row=lane&31, k=(lane>>5)*8+j (generalizes
// the verified 16x16x32 mapping); C/D: col=lane&31,
// row=(reg&3)+8*(reg>>2)+4*(lane>>5) [m74/m101].
// ---------------------------------------------------------------------------
#define GU_PHASE_SYNC()                                       \
    __builtin_amdgcn_s_barrier();                             \
    asm volatile("s_waitcnt lgkmcnt(0)" ::: "memory");        \
    __builtin_amdgcn_sched_barrier(0)

__global__ __launch_bounds__(512, 2) void gateup32_kernel(
    const u16* __restrict__ Yh, const u16* __restrict__ Yl,
    const u16* __restrict__ Gw, const u16* __restrict__ Uw,
    u16* __restrict__ FF)
{
    constexpr int NK = 32;                 // K=1024 / 32
    __shared__ u16 AsH[3][256 * 32];       // 48 KB
    __shared__ u16 AsL[3][256 * 32];       // 48 KB
    __shared__ u16 Gs[3][128 * 32];        // 24 KB
    __shared__ u16 Us[3][128 * 32];        // 24 KB  -> 144 KB total, 1 blk/CU

    const int tid  = threadIdx.x;
    const int lane = tid & 63;
    const int wave = tid >> 6;
    const int wave_m = wave >> 2;          // 0..1  -> A rows wave_m*128..+127
    const int wave_n = wave & 3;           // 0..3  -> B rows wave_n*32..+31

    // XCD-aware bijective swizzle: 512 wgs = 8 xcd * 64. Per XCD: 4 n-tiles
    // (gate+up panel 2 MB -> L2-resident), consecutive idx share the m-tile.
    const int wg  = blockIdx.x;
    const int xcd = wg & 7;
    const int idx = wg >> 3;               // 0..63
    const int ntile = xcd * 4 + (idx & 3); // 0..31
    const int mtile = idx >> 2;            // 0..15
    const int m0 = mtile * 256, n0 = ntile * 128;

    const int l31 = lane & 31;
    const int khi = lane >> 5;             // 0..1: k-subchunk within K=16

    f32x16 accg[4], accu[4];
    #pragma unroll
    for (int i = 0; i < 4; ++i) {
        accg[i] = (f32x16)(0.f);
        accu[i] = (f32x16)(0.f);
    }

    // ---- staging constants (512 thr * 16 B = 8 KB per issue) ----
    const int srow = tid >> 2;             // 0..127
    const int schk = tid & 3;
    const int sw   = schk ^ ((srow >> 1) & 3);   // same for srow+128 (128%4==0)
    const u16* aSrc0 = &Yh[(size_t)(m0 + srow) * 1024 + sw * 8];
    const u16* aSrc1 = &Yh[(size_t)(m0 + srow + 128) * 1024 + sw * 8];
    const u16* lSrc0 = &Yl[(size_t)(m0 + srow) * 1024 + sw * 8];
    const u16* lSrc1 = &Yl[(size_t)(m0 + srow + 128) * 1024 + sw * 8];
    const u16* gSrc  = &Gw[(size_t)(n0 + srow) * 1024 + sw * 8];
    const u16* uSrc  = &Uw[(size_t)(n0 + srow) * 1024 + sw * 8];
    const int aDst0 = srow * 32 + schk * 8;      // bytes = tid*16 (linear)
    const int aDst1 = aDst0 + 128 * 32;

#define STAGE_AH(T, BUF) do {                                  \
        async_copy16(aSrc0 + (T) * 32, &AsH[BUF][aDst0]);      \
        async_copy16(aSrc1 + (T) * 32, &AsH[BUF][aDst1]); } while (0)
#define STAGE_AL(T, BUF) do {                                  \
        async_copy16(lSrc0 + (T) * 32, &AsL[BUF][aDst0]);      \
        async_copy16(lSrc1 + (T) * 32, &AsL[BUF][aDst1]); } while (0)
#define STAGE_B(T, BUF) do {                                   \
        async_copy16(gSrc + (T) * 32, &Gs[BUF][aDst0]);        \
        async_copy16(uSrc + (T) * 32, &Us[BUF][aDst0]); } while (0)

    // ---- fragment read offsets (u16 units); logical chunk for khalf h is
    // 2h + khi, stored at (chunk ^ ((row>>1)&3)) ----
    int aOff[4][2], bOff[2];
    #pragma unroll
    for (int mf = 0; mf < 4; ++mf)
        #pragma unroll
        for (int h = 0; h < 2; ++h) {
            const int ra = wave_m * 128 + mf * 32 + l31;
            aOff[mf][h] = ra * 32 + (((2 * h + khi) ^ ((ra >> 1) & 3)) * 8);
        }
    #pragma unroll
    for (int h = 0; h < 2; ++h) {
        const int rb = wave_n * 32 + l31;
        bOff[h] = rb * 32 + (((2 * h + khi) ^ ((rb >> 1) & 3)) * 8);
    }

// One K-step: phase H (B frags + A-hi, 16 MFMA), phase L (A-lo, 16 MFMA).
// GATE: 6 = steady-state counted wait, 0 = drain (tail-1), -1 = none (last).
#define GU_STEP(BC, BN, T, PF, GATE) do {                                       \
    bf16x8 bg[2], bu[2];                                                        \
    {   /* ---- phase H ---- */                                                 \
        bf16x8 ah[4][2];                                                        \
        _Pragma("unroll")                                                       \
        for (int h = 0; h < 2; ++h) {                                           \
            bg[h] = *reinterpret_cast<const bf16x8*>(&Gs[BC][bOff[h]]);         \
            bu[h] = *reinterpret_cast<const bf16x8*>(&Us[BC][bOff[h]]);         \
        }                                                                       \
        _Pragma("unroll")                                                       \
        for (int mf = 0; mf < 4; ++mf)                                          \
            _Pragma("unroll")                                                   \
            for (int h = 0; h < 2; ++h)                                         \
                ah[mf][h] = *reinterpret_cast<const bf16x8*>(                   \
                    &AsH[BC][aOff[mf][h]]);                                     \
        if (PF) STAGE_AH((T) + 2, BN);                                          \
        GU_PHASE_SYNC();                                                        \
        __builtin_amdgcn_s_setprio(1);                                          \
        _Pragma("unroll")                                                       \
        for (int mf = 0; mf < 4; ++mf)                                          \
            _Pragma("unroll")                                                   \
            for (int h = 0; h < 2; ++h) {                                       \
                accg[mf] = __builtin_amdgcn_mfma_f32_32x32x16_bf16(             \
                    ah[mf][h], bg[h], accg[mf], 0, 0, 0);                       \
                accu[mf] = __builtin_amdgcn_mfma_f32_32x32x16_bf16(             \
                    ah[mf][h], bu[h], accu[mf], 0, 0, 0);                       \
            }                                                                   \
        __builtin_amdgcn_s_setprio(0);                                          \
        __builtin_amdgcn_s_barrier();                                           \
    }                                                                           \
    {   /* ---- phase L ---- */                                                 \
        bf16x8 al[4][2];                                                        \
        _Pragma("unroll")                                                       \
        for (int mf = 0; mf < 4; ++mf)                                          \
            _Pragma("unroll")                                                   \
            for (int h = 0; h < 2; ++h)                                         \
                al[mf][h] = *reinterpret_cast<const bf16x8*>(                   \
                    &AsL[BC][aOff[mf][h]]);                                     \
        if (PF) { STAGE_AL((T) + 2, BN); STAGE_B((T) + 2, BN); }                \
        GU_PHASE_SYNC();                                                        \
        __builtin_amdgcn_s_setprio(1);                                          \
        _Pragma("unroll")                                                       \
        for (int mf = 0; mf < 4; ++mf)                                          \
            _Pragma("unroll")                                                   \
            for (int h = 0; h < 2; ++h) {                                       \
                accg[mf] = __builtin_amdgcn_mfma_f32_32x32x16_bf16(             \
                    al[mf][h], bg[h], accg[mf], 0, 0, 0);                       \
                accu[mf] = __builtin_amdgcn_mfma_f32_32x32x16_bf16(             \
                    al[mf][h], bu[h], accu[mf], 0, 0, 0);                       \
            }                                                                   \
        __builtin_amdgcn_s_setprio(0);                                          \
        if ((GATE) == 6) {                                                      \
            asm volatile("s_waitcnt vmcnt(6)" ::: "memory");                    \
        } else if ((GATE) == 0) {                                               \
            asm volatile("s_waitcnt vmcnt(0)" ::: "memory");                    \
        }                                                                       \
        __builtin_amdgcn_s_barrier();                                           \
    }                                                                           \
} while (0)

    // ---- prologue: fill buffers 0 and 1 (12 loads in flight -> wait 6) ----
    STAGE_AH(0, 0); STAGE_AL(0, 0); STAGE_B(0, 0);
    STAGE_AH(1, 1); STAGE_AL(1, 1); STAGE_B(1, 1);
    asm volatile("s_waitcnt vmcnt(6)" ::: "memory");
    __builtin_amdgcn_s_barrier();

    // ---- main loop: unroll 3 -> all LDS buffer indices are literals ----
    #pragma unroll 1
    for (int t3 = 0; t3 < NK - 2; t3 += 3) {
        GU_STEP(0, 2, t3 + 0, true, 6);
        GU_STEP(1, 0, t3 + 1, true, 6);
        GU_STEP(2, 1, t3 + 2, true, 6);
    }
    // ---- tail: t=30 (buf0, drain to t=31's loads), t=31 (buf1) ----
    GU_STEP(0, 2, 30, false, 0);
    GU_STEP(1, 0, 31, false, -1);

#undef GU_STEP
#undef STAGE_AH
#undef STAGE_AL
#undef STAGE_B

    // ---- epilogue: silu(g)*u -> bf16 (32x32 C layout, m74/m101) ----
    #pragma unroll
    for (int mf = 0; mf < 4; ++mf)
        #pragma unroll
        for (int reg = 0; reg < 16; ++reg) {
            const int crow = (reg & 3) + 8 * (reg >> 2) + 4 * khi;
            const int gm = m0 + wave_m * 128 + mf * 32 + crow;
            const int gn = n0 + wave_n * 32 + l31;
            const float g = accg[mf][reg];
            const float ff = (g / (1.0f + __expf(-g))) * accu[mf][reg];
            FF[(size_t)gm * Ff + gn] = f2bf(ff);
        }
}

// ---------------------------------------------------------------------------
// MFMA flash attention v3 (EXACT r8 revert — one 16-row window per block;
// v4's window-pairing doubled the heaviest block's critical path and
// regressed; see r9 post-mortem).
// ---------------------------------------------------------------------------
__global__ __launch_bounds__(256) void attn_mfma_kernel(
    const u16* __restrict__ Qh, const u16* __restrict__ Ql,
    const u16* __restrict__ Kh, const u16* __restrict__ Kl,
    const u16* __restrict__ Vth, const u16* __restrict__ Vtl,
    u16* __restrict__ AOh, u16* __restrict__ AOl)
{
    __shared__ u16 KsH[64 * 72];
    __shared__ u16 KsL[64 * 72];
    __shared__ u16 VsH[64 * 72];
    __shared__ u16 VsL[64 * 72];
    __shared__ u16 Ps[4][16 * 72];

    const int tid = threadIdx.x;
    const int wave = tid >> 6, lane = tid & 63;
    const int l15 = lane & 15, quad = lane >> 4;

    const int bg = blockIdx.x & 7;
    const int b = bg >> 2, g = bg & 3;
    const int win = 127 - (blockIdx.x >> 3);
    const int t0 = win * 16;
    const int h = g * 4 + wave;

    bf16x8 qh[2], ql[2];
    {
        const size_t qrow = (size_t)(b * Tseq + t0 + l15) * 1024 + h * 64;
        #pragma unroll
        for (int ks = 0; ks < 2; ++ks) {
            qh[ks] = *reinterpret_cast<const bf16x8*>(&Qh[qrow + ks * 32 + quad * 8]);
            ql[ks] = *reinterpret_cast<const bf16x8*>(&Ql[qrow + ks * 32 + quad * 8]);
        }
    }

    const int srow = tid >> 2;
    const int scol = (tid & 3) * 16;
    const size_t kgb = (size_t)(b * Tseq) * 256 + g * 64 + scol;
    const size_t vgb = (size_t)(bg * 64 + srow) * Tseq + scol;

    const int nit = t0 / 64 + 1;

    uint4 ck0, ck1, cl0, cl1, cv0, cv1, cw0, cw1;
    {
        const size_t ka = kgb + (size_t)srow * 256;
        ck0 = *reinterpret_cast<const uint4*>(&Kh[ka]);
        ck1 = *reinterpret_cast<const uint4*>(&Kh[ka + 8]);
        cl0 = *reinterpret_cast<const uint4*>(&Kl[ka]);
        cl1 = *reinterpret_cast<const uint4*>(&Kl[ka + 8]);
        cv0 = *reinterpret_cast<const uint4*>(&Vth[vgb]);
        cv1 = *reinterpret_cast<const uint4*>(&Vth[vgb + 8]);
        cw0 = *reinterpret_cast<const uint4*>(&Vtl[vgb]);
        cw1 = *reinterpret_cast<const uint4*>(&Vtl[vgb + 8]);
    }

    f32x4 oacc[4];
    #pragma unroll
    for (int nt = 0; nt < 4; ++nt) oacc[nt] = (f32x4){0.f, 0.f, 0.f, 0.f};
    float m_r[4], l_r[4];
    #pragma unroll
    for (int r = 0; r < 4; ++r) { m_r[r] = -1e30f; l_r[r] = 0.0f; }

    u16* psw = &Ps[wave][0];
    const int lb = srow * 72 + scol;

    for (int it = 0; it < nit; ++it) {
        const int s0 = it * 64;
        const bool diag = (it == nit - 1);

        __syncthreads();
        *reinterpret_cast<uint4*>(&KsH[lb])     = ck0;
        *reinterpret_cast<uint4*>(&KsH[lb + 8]) = ck1;
        *reinterpret_cast<uint4*>(&KsL[lb])     = cl0;
        *reinterpret_cast<uint4*>(&KsL[lb + 8]) = cl1;
        *reinterpret_cast<uint4*>(&VsH[lb])     = cv0;
        *reinterpret_cast<uint4*>(&VsH[lb + 8]) = cv1;
        *reinterpret_cast<uint4*>(&VsL[lb])     = cw0;
        *reinterpret_cast<uint4*>(&VsL[lb + 8]) = cw1;
        if (it + 1 < nit) {
            const size_t ka = kgb + (size_t)(s0 + 64 + srow) * 256;
            ck0 = *reinterpret_cast<const uint4*>(&Kh[ka]);
            ck1 = *reinterpret_cast<const uint4*>(&Kh[ka + 8]);
            cl0 = *reinterpret_cast<const uint4*>(&Kl[ka]);
            cl1 = *reinterpret_cast<const uint4*>(&Kl[ka + 8]);
            const size_t va = vgb + s0 + 64;
            cv0 = *reinterpret_cast<const uint4*>(&Vth[va]);
            cv1 = *reinterpret_cast<const uint4*>(&Vth[va + 8]);
            cw0 = *reinterpret_cast<const uint4*>(&Vtl[va]);
            cw1 = *reinterpret_cast<const uint4*>(&Vtl[va + 8]);
        }
        __syncthreads();

        f32x4 sacc[4];
        #pragma unroll
        for (int nt = 0; nt < 4; ++nt) sacc[nt] = (f32x4){0.f, 0.f, 0.f, 0.f};

        #pragma unroll
        for (int ks = 0; ks < 2; ++ks) {
            bf16x8 kfh[4], kfl[4];
            #pragma unroll
            for (int nt = 0; nt < 4; ++nt) {
                const int a = (nt * 16 + l15) * 72 + ks * 32 + quad * 8;
                kfh[nt] = *reinterpret_cast<const bf16x8*>(&KsH[a]);
                kfl[nt] = *reinterpret_cast<const bf16x8*>(&KsL[a]);
            }
            #pragma unroll
            for (int nt = 0; nt < 4; ++nt) {
                sacc[nt] = __builtin_amdgcn_mfma_f32_16x16x32_bf16(qh[ks], kfh[nt], sacc[nt], 0, 0, 0);
                sacc[nt] = __builtin_amdgcn_mfma_f32_16x16x32_bf16(ql[ks], kfh[nt], sacc[nt], 0, 0, 0);
                sacc[nt] = __builtin_amdgcn_mfma_f32_16x16x32_bf16(qh[ks], kfl[nt], sacc[nt], 0, 0, 0);
            }
        }

        if (diag) {
            #pragma unroll
            for (int nt = 0; nt < 4; ++nt) {
                const int sg = s0 + nt * 16 + l15;
                #pragma unroll
                for (int r = 0; r < 4; ++r)
                    if (sg > t0 + quad * 4 + r) sacc[nt][r] = -1e30f;
            }
        }

        #pragma unroll
        for (int r = 0; r < 4; ++r) {
            float mx = fmaxf(fmaxf(sacc[0][r], sacc[1][r]),
                             fmaxf(sacc[2][r], sacc[3][r]));
            #pragma unroll
            for (int off = 1; off < 16; off <<= 1)
                mx = fmaxf(mx, __shfl_xor(mx, off, 16));
            const float mnew = fmaxf(m_r[r], mx);
            const float alpha = __expf(m_r[r] - mnew);
            m_r[r] = mnew;

            float rs = 0.0f;
            #pragma unroll
            for (int nt = 0; nt < 4; ++nt) {
                const float p = __expf(sacc[nt][r] - mnew);
                sacc[nt][r] = p;
                rs += p;
            }
            #pragma unroll
            for (int off = 1; off < 16; off <<= 1)
                rs += __shfl_xor(rs, off, 16);
            l_r[r] = l_r[r] * alpha + rs;
            #pragma unroll
            for (int nt = 0; nt < 4; ++nt) oacc[nt][r] *= alpha;
            #pragma unroll
            for (int nt = 0; nt < 4; ++nt)
                psw[(quad * 4 + r) * 72 + nt * 16 + l15] = f2bf(sacc[nt][r]);
        }

        #pragma unroll
        for (int ks = 0; ks < 2; ++ks) {
            const bf16x8 pa = *reinterpret_cast<const bf16x8*>(
                &psw[l15 * 72 + ks * 32 + quad * 8]);
            bf16x8 vfh[4], vfl[4];
            #pragma unroll
            for (int nt = 0; nt < 4; ++nt) {
                const int a = (nt * 16 + l15) * 72 + ks * 32 + quad * 8;
                vfh[nt] = *reinterpret_cast<const bf16x8*>(&VsH[a]);
                vfl[nt] = *reinterpret_cast<const bf16x8*>(&VsL[a]);
            }
            #pragma unroll
            for (int nt = 0; nt < 4; ++nt) {
                oacc[nt] = __builtin_amdgcn_mfma_f32_16x16x32_bf16(pa, vfh[nt], oacc[nt], 0, 0, 0);
                oacc[nt] = __builtin_amdgcn_mfma_f32_16x16x32_bf16(pa, vfl[nt], oacc[nt], 0, 0, 0);
            }
        }
    }

    #pragma unroll
    for (int r = 0; r < 4; ++r) {
        const float inv = 1.0f / l_r[r];
        const size_t orow = (size_t)(b * Tseq + t0 + quad * 4 + r) * 1024 + h * 64;
        #pragma unroll
        for (int nt = 0; nt < 4; ++nt) {
            const float o = oacc[nt][r] * inv;
            const u16 hi = f2bf(o);
            AOh[orow + nt * 16 + l15] = hi;
            AOl[orow + nt * 16 + l15] = f2bf(o - bf2f(hi));
        }
    }
}

// ---------------------------------------------------------------------------
// Host launcher
// ---------------------------------------------------------------------------
extern "C" void kernel_launch(void* const* d_in, const int* in_sizes, int n_in,
                              void* d_out, int out_size, void* d_ws,
                              size_t ws_size, hipStream_t stream)
{
    const float* hidden = (const float*)d_in[0];
    const float* sinp   = (const float*)d_in[1];
    const float* cosp   = (const float*)d_in[2];
    // d_in[3] = mask — causal, handled analytically
    const float* ln1    = (const float*)d_in[4];
    const float* ln2    = (const float*)d_in[5];
    const float* qn     = (const float*)d_in[6];
    const float* kn     = (const float*)d_in[7];
    const float* q_w    = (const float*)d_in[8];
    const float* k_w    = (const float*)d_in[9];
    const float* v_w    = (const float*)d_in[10];
    const float* o_w    = (const float*)d_in[11];
    const float* gate_w = (const float*)d_in[12];
    const float* up_w   = (const float*)d_in[13];
    const float* down_w = (const float*)d_in[14];
    float* out = (float*)d_out;

    // ---- workspace layout (116.4 MB; capacity >= 120.6 MB proven r8) ----
    char* base = (char*)d_ws;
    u16*   OTh  = (u16*)(base);                //  2 MB
    u16*   OTl  = (u16*)(base + 2097152);      //  2 MB
    u16*   GTh  = (u16*)(base + 4194304);      //  8 MB
    u16*   UTh  = (u16*)(base + 12582912);     //  8 MB
    u16*   DTh  = (u16*)(base + 20971520);     //  8 MB
    u16*   QKVT = (u16*)(base + 29360128);     //  3 MB
    u16*   Xh   = (u16*)(base + 32505856);     //  8 MB
    u16*   Qbh  = (u16*)(base + 40894464);     //  8 MB
    u16*   Qbl  = (u16*)(base + 49283072);     //  8 MB
    u16*   Kbh  = (u16*)(base + 57671680);     //  2 MB
    u16*   Kbl  = (u16*)(base + 59768832);     //  2 MB
    u16*   Vth  = (u16*)(base + 61865984);     //  2 MB
    u16*   Vtl  = (u16*)(base + 63963136);     //  2 MB
    u16*   AOh  = (u16*)(base + 66060288);     //  8 MB
    u16*   AOl  = (u16*)(base + 74448896);     //  8 MB
    u16*   FFh  = (u16*)(base + 82837504);     // 32 MB (end 116,391,936)

    // aliases (lifetime-checked):
    float* H2 = (float*)Qbh;   // 16 MB over Qbh+Qbl (Q dead post-attn)
    u16*   Yh = Kbh;           //  8 MB over Kbh..Vtl (K/V dead post-attn)
    u16*   Yl = AOh;           //  8 MB over AOh (AO dead post-o-proj)

    // 0. all weight prep, one launch
    wprep_all_kernel<<<14848, 256, 0, stream>>>(
        q_w, k_w, v_w, o_w, gate_w, up_w, down_w,
        QKVT, OTh, OTl, GTh, UTh, DTh);

    // 1. x = rmsnorm(hidden, ln1) -> bf16
    rmsnorm_split_kernel<0><<<Mrows, 256, 0, stream>>>(hidden, ln1, Xh, nullptr);

    // 2. fused qkv projection + qknorm + rope + split + V-transpose
    qkv_fused_kernel<<<dim3(12, 32), 256, 0, stream>>>(
        Xh, QKVT, qn, kn, sinp, cosp, Qbh, Qbl, Kbh, Kbl, Vth, Vtl);

    // 3. MFMA flash attention v3 (r8 revert) -> AO bf16 hi/lo
    attn_mfma_kernel<<<Bsz * Gg * (Tseq / 16), 256, 0, stream>>>(
        Qbh, Qbl, Kbh, Kbl, Vth, Vtl, AOh, AOl);

    // 4. hidden2 = hidden + attn @ o_w  (split x split)
    mfma_gemm_kernel<1, 1, 1><<<dim3(8, 32), 256, 0, stream>>>(
        AOh, AOl, OTh, OTl, hidden, H2, Mrows, Dmod, 1024);

    // 5. y = rmsnorm(hidden2, ln2) -> bf16 hi/lo
    rmsnorm_split_kernel<1><<<Mrows, 256, 0, stream>>>(H2, ln2, Yh, Yl);

    // 6. ff = silu(y@gate_w) * (y@up_w) -> FF bf16
    //    r11: 32x32x16 MFMA, 2 phases/K-step, triple-buffer unroll-3,
    //    counted vmcnt + setprio. 512 = 16 mtiles x 32 ntiles.
    gateup32_kernel<<<512, 512, 0, stream>>>(Yh, Yl, GTh, UTh, FFh);

    // 7. out = hidden2 + ff @ down_w
    mfma_gemm_kernel<0, 0, 1><<<dim3(8, 32), 256, 0, stream>>>(
        FFh, nullptr, DTh, nullptr, H2, out, Mrows, Dmod, 4096);
}

// Round 3
// 531.556 us; speedup vs baseline: 1.0052x; 1.0052x over previous
//
#include <hip/hip_runtime.h>
#include <hip/hip_bf16.h>

// Problem constants: B=2, T=2048, D=1024, H=16, G=4, K=64, F=4096
#define EPSF 1e-6f
constexpr int Bsz  = 2;
constexpr int Tseq = 2048;
constexpr int Dmod = 1024;
constexpr int Hh   = 16;
constexpr int Gg   = 4;
constexpr int Ff   = 4096;
constexpr int Mrows = Bsz * Tseq;          // 4096 tokens

typedef __attribute__((ext_vector_type(8))) short bf16x8;   // 8 bf16 (4 VGPRs)
typedef __attribute__((ext_vector_type(4))) float f32x4;
typedef __attribute__((ext_vector_type(16))) float f32x16;
typedef unsigned short u16;

// RNE fp32 -> bf16 (bit pattern as u16)
__device__ inline u16 f2bf(float x) {
    union { float f; unsigned u; } v; v.f = x;
    unsigned r = v.u + 0x7fff + ((v.u >> 16) & 1);
    return (u16)(r >> 16);
}
__device__ inline float bf2f(u16 h) {
    union { unsigned u; float f; } v; v.u = ((unsigned)h) << 16; return v.f;
}

// Async global->LDS DMA, 16 B per lane (wave-uniform base + lane*16).
__device__ __forceinline__ void async_copy16(const u16* g, u16* l) {
    __builtin_amdgcn_global_load_lds(
        (const __attribute__((address_space(1))) void*)g,
        (__attribute__((address_space(3))) void*)l, 16, 0, 0);
}

// Bank-swizzle notes. LDS tiles [row][32] bf16 (64 B rows), 4 chunks of 16 B.
// 16x16 kernels (rows span 16 per read): chunk q of row R stored at
// q ^ ((R>>1)&3) — verified conflict-free (r7/r10: SQ_LDS_BANK_CONFLICT = 0).
// 32x32 kernel (rows span 32 per read): r11 measured 1.05e7 conflicts with the
// same f. Model fit (r11 post-mortem): LDS processes wave64 b128 reads in
// lane-STRIDED groups (lanes = k mod 8); rows {r,r+8,r+16,r+24} share
// ((r>>1)&3) -> same chunk, same parity -> 4-way conflict. Fix: strengthen to
// f(R) = ((R>>1)&3) ^ ((R>>3)&3): rows 8/16/24 apart now XOR by 1/2/3 ->
// distinct chunks; <=2-way under consecutive grouping too.

// ---------------------------------------------------------------------------
// ALL weight prep in ONE launch (kept from r9 — sound). 14848 blocks.
// ---------------------------------------------------------------------------
__global__ __launch_bounds__(256) void wprep_all_kernel(
    const float* __restrict__ q_w, const float* __restrict__ k_w,
    const float* __restrict__ v_w, const float* __restrict__ o_w,
    const float* __restrict__ gate_w, const float* __restrict__ up_w,
    const float* __restrict__ down_w,
    u16* __restrict__ QKVT, u16* __restrict__ OTh, u16* __restrict__ OTl,
    u16* __restrict__ GTh, u16* __restrict__ UTh, u16* __restrict__ DTh)
{
    const int bx = blockIdx.x;
    const float* W; u16* Th; u16* Tl = nullptr;
    int N, Kd, ntile, ktile, drow;
    if (bx < 1024) {
        W = q_w; N = 1024; Kd = 1024; ntile = bx & 31; ktile = bx >> 5;
        Th = QKVT; drow = ntile * 32;
    } else if (bx < 1280) {
        const int i = bx - 1024;
        W = k_w; N = 256; Kd = 1024; ntile = i & 7; ktile = i >> 3;
        Th = QKVT; drow = 1024 + ntile * 32;
    } else if (bx < 1536) {
        const int i = bx - 1280;
        W = v_w; N = 256; Kd = 1024; ntile = i & 7; ktile = i >> 3;
        Th = QKVT; drow = 1280 + ntile * 32;
    } else if (bx < 2560) {
        const int i = bx - 1536;
        W = o_w; N = 1024; Kd = 1024; ntile = i & 31; ktile = i >> 5;
        Th = OTh; Tl = OTl; drow = ntile * 32;
    } else if (bx < 6656) {
        const int i = bx - 2560;
        W = gate_w; N = 4096; Kd = 1024; ntile = i & 127; ktile = i >> 7;
        Th = GTh; drow = ntile * 32;
    } else if (bx < 10752) {
        const int i = bx - 6656;
        W = up_w; N = 4096; Kd = 1024; ntile = i & 127; ktile = i >> 7;
        Th = UTh; drow = ntile * 32;
    } else {
        const int i = bx - 10752;
        W = down_w; N = 1024; Kd = 4096; ntile = i & 31; ktile = i >> 5;
        Th = DTh; drow = ntile * 32;
    }
    const int n0 = ntile * 32, k0 = ktile * 32;

    __shared__ float tile[32][33];
    const int r = threadIdx.x >> 3, c4 = (threadIdx.x & 7) * 4;
    const float4 v = *reinterpret_cast<const float4*>(&W[(size_t)(k0 + r) * N + n0 + c4]);
    tile[r][c4 + 0] = v.x; tile[r][c4 + 1] = v.y;
    tile[r][c4 + 2] = v.z; tile[r][c4 + 3] = v.w;
    __syncthreads();
    const int nl = threadIdx.x >> 3, kq = (threadIdx.x & 7) * 4;
    float x0 = tile[kq + 0][nl], x1 = tile[kq + 1][nl];
    float x2 = tile[kq + 2][nl], x3 = tile[kq + 3][nl];
    ushort4 h;
    h.x = f2bf(x0); h.y = f2bf(x1); h.z = f2bf(x2); h.w = f2bf(x3);
    *reinterpret_cast<ushort4*>(&Th[(size_t)(drow + nl) * Kd + k0 + kq]) = h;
    if (Tl) {
        ushort4 l;
        l.x = f2bf(x0 - bf2f(h.x)); l.y = f2bf(x1 - bf2f(h.y));
        l.z = f2bf(x2 - bf2f(h.z)); l.w = f2bf(x3 - bf2f(h.w));
        *reinterpret_cast<ushort4*>(&Tl[(size_t)(drow + nl) * Kd + k0 + kq]) = l;
    }
}

// ---------------------------------------------------------------------------
// RMSNorm over D=1024 -> bf16 hi (+ optional lo). One block per token.
// ---------------------------------------------------------------------------
template <int LO>
__global__ __launch_bounds__(256) void rmsnorm_split_kernel(
    const float* __restrict__ x, const float* __restrict__ scale,
    u16* __restrict__ oh, u16* __restrict__ ol)
{
    const int row = blockIdx.x;
    const int tid = threadIdx.x;
    const float4 v = reinterpret_cast<const float4*>(x + (size_t)row * Dmod)[tid];
    float ss = v.x * v.x + v.y * v.y + v.z * v.z + v.w * v.w;
    #pragma unroll
    for (int off = 32; off; off >>= 1) ss += __shfl_xor(ss, off, 64);
    __shared__ float part[4];
    if ((tid & 63) == 0) part[tid >> 6] = ss;
    __syncthreads();
    const float tot = part[0] + part[1] + part[2] + part[3];
    const float rstd = rsqrtf(tot * (1.0f / Dmod) + EPSF);
    const float4 sc = reinterpret_cast<const float4*>(scale)[tid];
    float o0 = v.x * rstd * sc.x, o1 = v.y * rstd * sc.y;
    float o2 = v.z * rstd * sc.z, o3 = v.w * rstd * sc.w;
    ushort4 h;
    h.x = f2bf(o0); h.y = f2bf(o1); h.z = f2bf(o2); h.w = f2bf(o3);
    *reinterpret_cast<ushort4*>(&oh[(size_t)row * Dmod + tid * 4]) = h;
    if (LO) {
        ushort4 l;
        l.x = f2bf(o0 - bf2f(h.x)); l.y = f2bf(o1 - bf2f(h.y));
        l.z = f2bf(o2 - bf2f(h.z)); l.w = f2bf(o3 - bf2f(h.w));
        *reinterpret_cast<ushort4*>(&ol[(size_t)row * Dmod + tid * 4]) = l;
    }
}

// ---------------------------------------------------------------------------
// Split-bf16 MFMA GEMM, async DMA + swizzle (unchanged from r7).
// ---------------------------------------------------------------------------
template <int ASPLIT, int BSPLIT, int RES>
__global__ __launch_bounds__(256, 2) void mfma_gemm_kernel(
    const u16* __restrict__ Ah, const u16* __restrict__ Al,
    const u16* __restrict__ Bh, const u16* __restrict__ Bl,
    const float* __restrict__ res, float* __restrict__ C,
    int M, int N, int Kd)
{
    __shared__ u16 As_h[128 * 32];
    __shared__ u16 As_l[128 * 32];
    __shared__ u16 Bs_h[128 * 32];
    __shared__ u16 Bs_l[128 * 32];

    const int tid = threadIdx.x;
    const int lane = tid & 63, wave = tid >> 6;
    const int wm = (wave >> 1) * 64, wn = (wave & 1) * 64;
    const int m0 = blockIdx.y * 128, n0 = blockIdx.x * 128;
    const int fm = lane & 15, quad = lane >> 4;
    const int fsw = (fm >> 1) & 3;
    const int fcol = ((quad ^ fsw) * 8);

    f32x4 acc[4][4];
    #pragma unroll
    for (int i = 0; i < 4; ++i)
        #pragma unroll
        for (int j = 0; j < 4; ++j) acc[i][j] = (f32x4){0.f, 0.f, 0.f, 0.f};

    const int lrow = lane >> 2;
    const int lchunk = lane & 3;
    const int schunk = lchunk ^ ((lrow >> 1) & 3);

    for (int k0 = 0; k0 < Kd; k0 += 32) {
        __syncthreads();
        #pragma unroll
        for (int p = 0; p < 2; ++p) {
            const int row = wave * 32 + p * 16 + lrow;
            const size_t ga = (size_t)(m0 + row) * Kd + k0 + schunk * 8;
            const size_t gb = (size_t)(n0 + row) * Kd + k0 + schunk * 8;
            const int ls = row * 32 + lchunk * 8;
            async_copy16(&Ah[ga], &As_h[ls]);
            if (ASPLIT) async_copy16(&Al[ga], &As_l[ls]);
            async_copy16(&Bh[gb], &Bs_h[ls]);
            if (BSPLIT) async_copy16(&Bl[gb], &Bs_l[ls]);
        }
        __syncthreads();

        bf16x8 ah[4], al[4], bh[4], bl[4];
        #pragma unroll
        for (int t = 0; t < 4; ++t) {
            const int ra = (wm + t * 16 + fm) * 32 + fcol;
            const int rb = (wn + t * 16 + fm) * 32 + fcol;
            ah[t] = *reinterpret_cast<const bf16x8*>(&As_h[ra]);
            bh[t] = *reinterpret_cast<const bf16x8*>(&Bs_h[rb]);
            if (ASPLIT) al[t] = *reinterpret_cast<const bf16x8*>(&As_l[ra]);
            if (BSPLIT) bl[t] = *reinterpret_cast<const bf16x8*>(&Bs_l[rb]);
        }
        #pragma unroll
        for (int mt = 0; mt < 4; ++mt)
            #pragma unroll
            for (int nt = 0; nt < 4; ++nt) {
                acc[mt][nt] = __builtin_amdgcn_mfma_f32_16x16x32_bf16(
                    ah[mt], bh[nt], acc[mt][nt], 0, 0, 0);
                if (BSPLIT)
                    acc[mt][nt] = __builtin_amdgcn_mfma_f32_16x16x32_bf16(
                        ah[mt], bl[nt], acc[mt][nt], 0, 0, 0);
                if (ASPLIT)
                    acc[mt][nt] = __builtin_amdgcn_mfma_f32_16x16x32_bf16(
                        al[mt], bh[nt], acc[mt][nt], 0, 0, 0);
            }
    }

    const int cr = (lane >> 4) * 4, cn = lane & 15;
    #pragma unroll
    for (int mt = 0; mt < 4; ++mt)
        #pragma unroll
        for (int nt = 0; nt < 4; ++nt)
            #pragma unroll
            for (int r = 0; r < 4; ++r) {
                const int gm = m0 + wm + mt * 16 + cr + r;
                const int gn = n0 + wn + nt * 16 + cn;
                float v = acc[mt][nt][r];
                if (RES) v += res[(size_t)gm * N + gn];
                C[(size_t)gm * N + gn] = v;
            }
}

// ---------------------------------------------------------------------------
// Fused QKV GEMM + qk-norm + RoPE + bf16 split epilogue; V stored TRANSPOSED
// directly (kept from r9 — sound).
// ---------------------------------------------------------------------------
__global__ __launch_bounds__(256, 2) void qkv_fused_kernel(
    const u16* __restrict__ Ah, const u16* __restrict__ Bh,
    const float* __restrict__ qn, const float* __restrict__ kn,
    const float* __restrict__ sinp, const float* __restrict__ cosp,
    u16* __restrict__ Qbh, u16* __restrict__ Qbl,
    u16* __restrict__ Kbh, u16* __restrict__ Kbl,
    u16* __restrict__ Vth, u16* __restrict__ Vtl)
{
    __shared__ u16 As_h[128 * 32];
    __shared__ u16 Bs_h[128 * 32];

    const int Kd = 1024;
    const int tid = threadIdx.x;
    const int lane = tid & 63, wave = tid >> 6;
    const int wm = (wave >> 1) * 64, wn = (wave & 1) * 64;
    const int m0 = blockIdx.y * 128, n0 = blockIdx.x * 128;
    const int fm = lane & 15, quad = lane >> 4;
    const int fsw = (fm >> 1) & 3;
    const int fcol = ((quad ^ fsw) * 8);

    f32x4 acc[4][4];
    #pragma unroll
    for (int i = 0; i < 4; ++i)
        #pragma unroll
        for (int j = 0; j < 4; ++j) acc[i][j] = (f32x4){0.f, 0.f, 0.f, 0.f};

    const int lrow = lane >> 2;
    const int lchunk = lane & 3;
    const int schunk = lchunk ^ ((lrow >> 1) & 3);

    for (int k0 = 0; k0 < Kd; k0 += 32) {
        __syncthreads();
        #pragma unroll
        for (int p = 0; p < 2; ++p) {
            const int row = wave * 32 + p * 16 + lrow;
            const size_t ga = (size_t)(m0 + row) * Kd + k0 + schunk * 8;
            const size_t gb = (size_t)(n0 + row) * Kd + k0 + schunk * 8;
            const int ls = row * 32 + lchunk * 8;
            async_copy16(&Ah[ga], &As_h[ls]);
            async_copy16(&Bh[gb], &Bs_h[ls]);
        }
        __syncthreads();

        bf16x8 ah[4], bh[4];
        #pragma unroll
        for (int t = 0; t < 4; ++t) {
            ah[t] = *reinterpret_cast<const bf16x8*>(&As_h[(wm + t * 16 + fm) * 32 + fcol]);
            bh[t] = *reinterpret_cast<const bf16x8*>(&Bs_h[(wn + t * 16 + fm) * 32 + fcol]);
        }
        #pragma unroll
        for (int mt = 0; mt < 4; ++mt)
            #pragma unroll
            for (int nt = 0; nt < 4; ++nt)
                acc[mt][nt] = __builtin_amdgcn_mfma_f32_16x16x32_bf16(
                    ah[mt], bh[nt], acc[mt][nt], 0, 0, 0);
    }

    const int gn0 = n0 + wn;          // wave col base, 64-aligned
    const int l15 = lane & 15;

    if (gn0 < 1280) {
        // ---- Q or K: per-head RMSNorm + RoPE + split ----
        const bool isQ = (gn0 < 1024);
        const float* nsc = isQ ? qn : kn;
        const float osc = isQ ? 0.125f : 1.0f;
        u16* __restrict__ oh = isQ ? Qbh : Kbh;
        u16* __restrict__ ol = isQ ? Qbl : Kbl;
        const int rowstride = isQ ? 1024 : 256;
        const int colbase = isQ ? gn0 : gn0 - 1024;
        float sc[4];
        #pragma unroll
        for (int nt = 0; nt < 4; ++nt) sc[nt] = nsc[nt * 16 + l15];

        #pragma unroll
        for (int mt = 0; mt < 4; ++mt)
            #pragma unroll
            for (int r = 0; r < 4; ++r) {
                const int bt = m0 + wm + mt * 16 + quad * 4 + r;
                float v[4];
                #pragma unroll
                for (int nt = 0; nt < 4; ++nt) v[nt] = acc[mt][nt][r];
                float ss = v[0] * v[0] + v[1] * v[1] + v[2] * v[2] + v[3] * v[3];
                #pragma unroll
                for (int off = 1; off < 16; off <<= 1)
                    ss += __shfl_xor(ss, off, 16);
                const float rstd = rsqrtf(ss * (1.0f / 64.0f) + EPSF);
                float nv[4];
                #pragma unroll
                for (int nt = 0; nt < 4; ++nt) nv[nt] = v[nt] * rstd * sc[nt];
                const float s0 = sinp[bt * 32 + l15];
                const float c0 = cosp[bt * 32 + l15];
                const float s1 = sinp[bt * 32 + 16 + l15];
                const float c1 = cosp[bt * 32 + 16 + l15];
                float o[4];
                o[0] = (nv[0] * c0 - nv[2] * s0) * osc;
                o[1] = (nv[1] * c1 - nv[3] * s1) * osc;
                o[2] = (nv[2] * c0 + nv[0] * s0) * osc;
                o[3] = (nv[3] * c1 + nv[1] * s1) * osc;
                #pragma unroll
                for (int nt = 0; nt < 4; ++nt) {
                    const size_t off = (size_t)bt * rowstride + colbase + nt * 16 + l15;
                    const u16 hi = f2bf(o[nt]);
                    oh[off] = hi;
                    ol[off] = f2bf(o[nt] - bf2f(hi));
                }
            }
    } else {
        // ---- V: bf16 split, stored transposed: Vt[(b*4+g)*64+d][t] ----
        const int g = (gn0 - 1280) >> 6;
        const int b = (m0 + wm) >> 11;
        const int tb = ((m0 + wm) & 2047) + quad * 4;
        #pragma unroll
        for (int mt = 0; mt < 4; ++mt)
            #pragma unroll
            for (int nt = 0; nt < 4; ++nt) {
                const float v0 = acc[mt][nt][0], v1 = acc[mt][nt][1];
                const float v2 = acc[mt][nt][2], v3 = acc[mt][nt][3];
                ushort4 hv, lv;
                hv.x = f2bf(v0); hv.y = f2bf(v1); hv.z = f2bf(v2); hv.w = f2bf(v3);
                lv.x = f2bf(v0 - bf2f(hv.x)); lv.y = f2bf(v1 - bf2f(hv.y));
                lv.z = f2bf(v2 - bf2f(hv.z)); lv.w = f2bf(v3 - bf2f(hv.w));
                const size_t off =
                    ((size_t)((b * 4 + g) * 64 + nt * 16 + l15)) * Tseq + tb + mt * 16;
                *reinterpret_cast<ushort4*>(&Vth[off]) = hv;
                *reinterpret_cast<ushort4*>(&Vtl[off]) = lv;
            }
    }
}

// ---------------------------------------------------------------------------
// Fused gate/up GEMM, r12: r11 structure (32x32x16 MFMA, 256x128 tile, 512
// thr, 2 phases/K-step, triple-buffer unroll-3, counted vmcnt, setprio) with
// STRENGTHENED chunk swizzle f(R) = ((R>>1)&3) ^ ((R>>3)&3). r11's f missed
// rows 8/16/24 apart (strided-group 4-way conflicts, 1.05e7 measured); new f
// makes them distinct. Numerics identical to r11 (same data, same order).
// ---------------------------------------------------------------------------
#define GU_PHASE_SYNC()                                       \
    __builtin_amdgcn_s_barrier();                             \
    asm volatile("s_waitcnt lgkmcnt(0)" ::: "memory");        \
    __builtin_amdgcn_sched_barrier(0)

__global__ __launch_bounds__(512, 2) void gateup32_kernel(
    const u16* __restrict__ Yh, const u16* __restrict__ Yl,
    const u16* __restrict__ Gw, const u16* __restrict__ Uw,
    u16* __restrict__ FF)
{
    constexpr int NK = 32;                 // K=1024 / 32
    __shared__ u16 AsH[3][256 * 32];       // 48 KB
    __shared__ u16 AsL[3][256 * 32];       // 48 KB
    __shared__ u16 Gs[3][128 * 32];        // 24 KB
    __shared__ u16 Us[3][128 * 32];        // 24 KB  -> 144 KB total, 1 blk/CU

    const int tid  = threadIdx.x;
    const int lane = tid & 63;
    const int wave = tid >> 6;
    const int wave_m = wave >> 2;          // 0..1  -> A rows wave_m*128..+127
    const int wave_n = wave & 3;           // 0..3  -> B rows wave_n*32..+31

    // XCD-aware bijective swizzle: 512 wgs = 8 xcd * 64. Per XCD: 4 n-tiles
    // (gate+up panel 2 MB -> L2-resident), consecutive idx share the m-tile.
    const int wg  = blockIdx.x;
    const int xcd = wg & 7;
    const int idx = wg >> 3;               // 0..63
    const int ntile = xcd * 4 + (idx & 3); // 0..31
    const int mtile = idx >> 2;            // 0..15
    const int m0 = mtile * 256, n0 = ntile * 128;

    const int l31 = lane & 31;
    const int khi = lane >> 5;             // 0..1: k-subchunk within K=16

    f32x16 accg[4], accu[4];
    #pragma unroll
    for (int i = 0; i < 4; ++i) {
        accg[i] = (f32x16)(0.f);
        accu[i] = (f32x16)(0.f);
    }

    // ---- staging constants (512 thr * 16 B = 8 KB per issue) ----
    const int srow = tid >> 2;             // 0..127
    const int schk = tid & 3;
    // f(R) = ((R>>1)&3) ^ ((R>>3)&3); f(srow+128) == f(srow) (128>>3=16, &3=0)
    const int sw   = schk ^ (((srow >> 1) & 3) ^ ((srow >> 3) & 3));
    const u16* aSrc0 = &Yh[(size_t)(m0 + srow) * 1024 + sw * 8];
    const u16* aSrc1 = &Yh[(size_t)(m0 + srow + 128) * 1024 + sw * 8];
    const u16* lSrc0 = &Yl[(size_t)(m0 + srow) * 1024 + sw * 8];
    const u16* lSrc1 = &Yl[(size_t)(m0 + srow + 128) * 1024 + sw * 8];
    const u16* gSrc  = &Gw[(size_t)(n0 + srow) * 1024 + sw * 8];
    const u16* uSrc  = &Uw[(size_t)(n0 + srow) * 1024 + sw * 8];
    const int aDst0 = srow * 32 + schk * 8;      // bytes = tid*16 (linear)
    const int aDst1 = aDst0 + 128 * 32;

#define STAGE_AH(T, BUF) do {                                  \
        async_copy16(aSrc0 + (T) * 32, &AsH[BUF][aDst0]);      \
        async_copy16(aSrc1 + (T) * 32, &AsH[BUF][aDst1]); } while (0)
#define STAGE_AL(T, BUF) do {                                  \
        async_copy16(lSrc0 + (T) * 32, &AsL[BUF][aDst0]);      \
        async_copy16(lSrc1 + (T) * 32, &AsL[BUF][aDst1]); } while (0)
#define STAGE_B(T, BUF) do {                                   \
        async_copy16(gSrc + (T) * 32, &Gs[BUF][aDst0]);        \
        async_copy16(uSrc + (T) * 32, &Us[BUF][aDst0]); } while (0)

    // ---- fragment read offsets (u16 units); logical chunk for khalf h is
    // 2h + khi, stored at (chunk ^ f(row)) ----
    int aOff[4][2], bOff[2];
    #pragma unroll
    for (int mf = 0; mf < 4; ++mf)
        #pragma unroll
        for (int h = 0; h < 2; ++h) {
            const int ra = wave_m * 128 + mf * 32 + l31;
            const int fr = ((ra >> 1) & 3) ^ ((ra >> 3) & 3);
            aOff[mf][h] = ra * 32 + (((2 * h + khi) ^ fr) * 8);
        }
    #pragma unroll
    for (int h = 0; h < 2; ++h) {
        const int rb = wave_n * 32 + l31;
        const int fr = ((rb >> 1) & 3) ^ ((rb >> 3) & 3);
        bOff[h] = rb * 32 + (((2 * h + khi) ^ fr) * 8);
    }

// One K-step: phase H (B frags + A-hi, 16 MFMA), phase L (A-lo, 16 MFMA).
// GATE: 6 = steady-state counted wait, 0 = drain (tail-1), -1 = none (last).
#define GU_STEP(BC, BN, T, PF, GATE) do {                                       \
    bf16x8 bg[2], bu[2];                                                        \
    {   /* ---- phase H ---- */                                                 \
        bf16x8 ah[4][2];                                                        \
        _Pragma("unroll")                                                       \
        for (int h = 0; h < 2; ++h) {                                           \
            bg[h] = *reinterpret_cast<const bf16x8*>(&Gs[BC][bOff[h]]);         \
            bu[h] = *reinterpret_cast<const bf16x8*>(&Us[BC][bOff[h]]);         \
        }                                                                       \
        _Pragma("unroll")                                                       \
        for (int mf = 0; mf < 4; ++mf)                                          \
            _Pragma("unroll")                                                   \
            for (int h = 0; h < 2; ++h)                                         \
                ah[mf][h] = *reinterpret_cast<const bf16x8*>(                   \
                    &AsH[BC][aOff[mf][h]]);                                     \
        if (PF) STAGE_AH((T) + 2, BN);                                          \
        GU_PHASE_SYNC();                                                        \
        __builtin_amdgcn_s_setprio(1);                                          \
        _Pragma("unroll")                                                       \
        for (int mf = 0; mf < 4; ++mf)                                          \
            _Pragma("unroll")                                                   \
            for (int h = 0; h < 2; ++h) {                                       \
                accg[mf] = __builtin_amdgcn_mfma_f32_32x32x16_bf16(             \
                    ah[mf][h], bg[h], accg[mf], 0, 0, 0);                       \
                accu[mf] = __builtin_amdgcn_mfma_f32_32x32x16_bf16(             \
                    ah[mf][h], bu[h], accu[mf], 0, 0, 0);                       \
            }                                                                   \
        __builtin_amdgcn_s_setprio(0);                                          \
        __builtin_amdgcn_s_barrier();                                           \
    }                                                                           \
    {   /* ---- phase L ---- */                                                 \
        bf16x8 al[4][2];                                                        \
        _Pragma("unroll")                                                       \
        for (int mf = 0; mf < 4; ++mf)                                          \
            _Pragma("unroll")                                                   \
            for (int h = 0; h < 2; ++h)                                         \
                al[mf][h] = *reinterpret_cast<const bf16x8*>(                   \
                    &AsL[BC][aOff[mf][h]]);                                     \
        if (PF) { STAGE_AL((T) + 2, BN); STAGE_B((T) + 2, BN); }                \
        GU_PHASE_SYNC();                                                        \
        __builtin_amdgcn_s_setprio(1);                                          \
        _Pragma("unroll")                                                       \
        for (int mf = 0; mf < 4; ++mf)                                          \
            _Pragma("unroll")                                                   \
            for (int h = 0; h < 2; ++h) {                                       \
                accg[mf] = __builtin_amdgcn_mfma_f32_32x32x16_bf16(             \
                    al[mf][h], bg[h], accg[mf], 0, 0, 0);                       \
                accu[mf] = __builtin_amdgcn_mfma_f32_32x32x16_bf16(             \
                    al[mf][h], bu[h], accu[mf], 0, 0, 0);                       \
            }                                                                   \
        __builtin_amdgcn_s_setprio(0);                                          \
        if ((GATE) == 6) {                                                      \
            asm volatile("s_waitcnt vmcnt(6)" ::: "memory");                    \
        } else if ((GATE) == 0) {                                               \
            asm volatile("s_waitcnt vmcnt(0)" ::: "memory");                    \
        }                                                                       \
        __builtin_amdgcn_s_barrier();                                           \
    }                                                                           \
} while (0)

    // ---- prologue: fill buffers 0 and 1 (12 loads in flight -> wait 6) ----
    STAGE_AH(0, 0); STAGE_AL(0, 0); STAGE_B(0, 0);
    STAGE_AH(1, 1); STAGE_AL(1, 1); STAGE_B(1, 1);
    asm volatile("s_waitcnt vmcnt(6)" ::: "memory");
    __builtin_amdgcn_s_barrier();

    // ---- main loop: unroll 3 -> all LDS buffer indices are literals ----
    #pragma unroll 1
    for (int t3 = 0; t3 < NK - 2; t3 += 3) {
        GU_STEP(0, 2, t3 + 0, true, 6);
        GU_STEP(1, 0, t3 + 1, true, 6);
        GU_STEP(2, 1, t3 + 2, true, 6);
    }
    // ---- tail: t=30 (buf0, drain to t=31's loads), t=31 (buf1) ----
    GU_STEP(0, 2, 30, false, 0);
    GU_STEP(1, 0, 31, false, -1);

#undef GU_STEP
#undef STAGE_AH
#undef STAGE_AL
#undef STAGE_B

    // ---- epilogue: silu(g)*u -> bf16 (32x32 C layout, m74/m101) ----
    #pragma unroll
    for (int mf = 0; mf < 4; ++mf)
        #pragma unroll
        for (int reg = 0; reg < 16; ++reg) {
            const int crow = (reg & 3) + 8 * (reg >> 2) + 4 * khi;
            const int gm = m0 + wave_m * 128 + mf * 32 + crow;
            const int gn = n0 + wave_n * 32 + l31;
            const float g = accg[mf][reg];
            const float ff = (g / (1.0f + __expf(-g))) * accu[mf][reg];
            FF[(size_t)gm * Ff + gn] = f2bf(ff);
        }
}

// ---------------------------------------------------------------------------
// MFMA flash attention v3 (EXACT r8 revert — one 16-row window per block;
// v4's window-pairing doubled the heaviest block's critical path and
// regressed; see r9 post-mortem).
// ---------------------------------------------------------------------------
__global__ __launch_bounds__(256) void attn_mfma_kernel(
    const u16* __restrict__ Qh, const u16* __restrict__ Ql,
    const u16* __restrict__ Kh, const u16* __restrict__ Kl,
    const u16* __restrict__ Vth, const u16* __restrict__ Vtl,
    u16* __restrict__ AOh, u16* __restrict__ AOl)
{
    __shared__ u16 KsH[64 * 72];
    __shared__ u16 KsL[64 * 72];
    __shared__ u16 VsH[64 * 72];
    __shared__ u16 VsL[64 * 72];
    __shared__ u16 Ps[4][16 * 72];

    const int tid = threadIdx.x;
    const int wave = tid >> 6, lane = tid & 63;
    const int l15 = lane & 15, quad = lane >> 4;

    const int bg = blockIdx.x & 7;
    const int b = bg >> 2, g = bg & 3;
    const int win = 127 - (blockIdx.x >> 3);
    const int t0 = win * 16;
    const int h = g * 4 + wave;

    bf16x8 qh[2], ql[2];
    {
        const size_t qrow = (size_t)(b * Tseq + t0 + l15) * 1024 + h * 64;
        #pragma unroll
        for (int ks = 0; ks < 2; ++ks) {
            qh[ks] = *reinterpret_cast<const bf16x8*>(&Qh[qrow + ks * 32 + quad * 8]);
            ql[ks] = *reinterpret_cast<const bf16x8*>(&Ql[qrow + ks * 32 + quad * 8]);
        }
    }

    const int srow = tid >> 2;
    const int scol = (tid & 3) * 16;
    const size_t kgb = (size_t)(b * Tseq) * 256 + g * 64 + scol;
    const size_t vgb = (size_t)(bg * 64 + srow) * Tseq + scol;

    const int nit = t0 / 64 + 1;

    uint4 ck0, ck1, cl0, cl1, cv0, cv1, cw0, cw1;
    {
        const size_t ka = kgb + (size_t)srow * 256;
        ck0 = *reinterpret_cast<const uint4*>(&Kh[ka]);
        ck1 = *reinterpret_cast<const uint4*>(&Kh[ka + 8]);
        cl0 = *reinterpret_cast<const uint4*>(&Kl[ka]);
        cl1 = *reinterpret_cast<const uint4*>(&Kl[ka + 8]);
        cv0 = *reinterpret_cast<const uint4*>(&Vth[vgb]);
        cv1 = *reinterpret_cast<const uint4*>(&Vth[vgb + 8]);
        cw0 = *reinterpret_cast<const uint4*>(&Vtl[vgb]);
        cw1 = *reinterpret_cast<const uint4*>(&Vtl[vgb + 8]);
    }

    f32x4 oacc[4];
    #pragma unroll
    for (int nt = 0; nt < 4; ++nt) oacc[nt] = (f32x4){0.f, 0.f, 0.f, 0.f};
    float m_r[4], l_r[4];
    #pragma unroll
    for (int r = 0; r < 4; ++r) { m_r[r] = -1e30f; l_r[r] = 0.0f; }

    u16* psw = &Ps[wave][0];
    const int lb = srow * 72 + scol;

    for (int it = 0; it < nit; ++it) {
        const int s0 = it * 64;
        const bool diag = (it == nit - 1);

        __syncthreads();
        *reinterpret_cast<uint4*>(&KsH[lb])     = ck0;
        *reinterpret_cast<uint4*>(&KsH[lb + 8]) = ck1;
        *reinterpret_cast<uint4*>(&KsL[lb])     = cl0;
        *reinterpret_cast<uint4*>(&KsL[lb + 8]) = cl1;
        *reinterpret_cast<uint4*>(&VsH[lb])     = cv0;
        *reinterpret_cast<uint4*>(&VsH[lb + 8]) = cv1;
        *reinterpret_cast<uint4*>(&VsL[lb])     = cw0;
        *reinterpret_cast<uint4*>(&VsL[lb + 8]) = cw1;
        if (it + 1 < nit) {
            const size_t ka = kgb + (size_t)(s0 + 64 + srow) * 256;
            ck0 = *reinterpret_cast<const uint4*>(&Kh[ka]);
            ck1 = *reinterpret_cast<const uint4*>(&Kh[ka + 8]);
            cl0 = *reinterpret_cast<const uint4*>(&Kl[ka]);
            cl1 = *reinterpret_cast<const uint4*>(&Kl[ka + 8]);
            const size_t va = vgb + s0 + 64;
            cv0 = *reinterpret_cast<const uint4*>(&Vth[va]);
            cv1 = *reinterpret_cast<const uint4*>(&Vth[va + 8]);
            cw0 = *reinterpret_cast<const uint4*>(&Vtl[va]);
            cw1 = *reinterpret_cast<const uint4*>(&Vtl[va + 8]);
        }
        __syncthreads();

        f32x4 sacc[4];
        #pragma unroll
        for (int nt = 0; nt < 4; ++nt) sacc[nt] = (f32x4){0.f, 0.f, 0.f, 0.f};

        #pragma unroll
        for (int ks = 0; ks < 2; ++ks) {
            bf16x8 kfh[4], kfl[4];
            #pragma unroll
            for (int nt = 0; nt < 4; ++nt) {
                const int a = (nt * 16 + l15) * 72 + ks * 32 + quad * 8;
                kfh[nt] = *reinterpret_cast<const bf16x8*>(&KsH[a]);
                kfl[nt] = *reinterpret_cast<const bf16x8*>(&KsL[a]);
            }
            #pragma unroll
            for (int nt = 0; nt < 4; ++nt) {
                sacc[nt] = __builtin_amdgcn_mfma_f32_16x16x32_bf16(qh[ks], kfh[nt], sacc[nt], 0, 0, 0);
                sacc[nt] = __builtin_amdgcn_mfma_f32_16x16x32_bf16(ql[ks], kfh[nt], sacc[nt], 0, 0, 0);
                sacc[nt] = __builtin_amdgcn_mfma_f32_16x16x32_bf16(qh[ks], kfl[nt], sacc[nt], 0, 0, 0);
            }
        }

        if (diag) {
            #pragma unroll
            for (int nt = 0; nt < 4; ++nt) {
                const int sg = s0 + nt * 16 + l15;
                #pragma unroll
                for (int r = 0; r < 4; ++r)
                    if (sg > t0 + quad * 4 + r) sacc[nt][r] = -1e30f;
            }
        }

        #pragma unroll
        for (int r = 0; r < 4; ++r) {
            float mx = fmaxf(fmaxf(sacc[0][r], sacc[1][r]),
                             fmaxf(sacc[2][r], sacc[3][r]));
            #pragma unroll
            for (int off = 1; off < 16; off <<= 1)
                mx = fmaxf(mx, __shfl_xor(mx, off, 16));
            const float mnew = fmaxf(m_r[r], mx);
            const float alpha = __expf(m_r[r] - mnew);
            m_r[r] = mnew;

            float rs = 0.0f;
            #pragma unroll
            for (int nt = 0; nt < 4; ++nt) {
                const float p = __expf(sacc[nt][r] - mnew);
                sacc[nt][r] = p;
                rs += p;
            }
            #pragma unroll
            for (int off = 1; off < 16; off <<= 1)
                rs += __shfl_xor(rs, off, 16);
            l_r[r] = l_r[r] * alpha + rs;
            #pragma unroll
            for (int nt = 0; nt < 4; ++nt) oacc[nt][r] *= alpha;
            #pragma unroll
            for (int nt = 0; nt < 4; ++nt)
                psw[(quad * 4 + r) * 72 + nt * 16 + l15] = f2bf(sacc[nt][r]);
        }

        #pragma unroll
        for (int ks = 0; ks < 2; ++ks) {
            const bf16x8 pa = *reinterpret_cast<const bf16x8*>(
                &psw[l15 * 72 + ks * 32 + quad * 8]);
            bf16x8 vfh[4], vfl[4];
            #pragma unroll
            for (int nt = 0; nt < 4; ++nt) {
                const int a = (nt * 16 + l15) * 72 + ks * 32 + quad * 8;
                vfh[nt] = *reinterpret_cast<const bf16x8*>(&VsH[a]);
                vfl[nt] = *reinterpret_cast<const bf16x8*>(&VsL[a]);
            }
            #pragma unroll
            for (int nt = 0; nt < 4; ++nt) {
                oacc[nt] = __builtin_amdgcn_mfma_f32_16x16x32_bf16(pa, vfh[nt], oacc[nt], 0, 0, 0);
                oacc[nt] = __builtin_amdgcn_mfma_f32_16x16x32_bf16(pa, vfl[nt], oacc[nt], 0, 0, 0);
            }
        }
    }

    #pragma unroll
    for (int r = 0; r < 4; ++r) {
        const float inv = 1.0f / l_r[r];
        const size_t orow = (size_t)(b * Tseq + t0 + quad * 4 + r) * 1024 + h * 64;
        #pragma unroll
        for (int nt = 0; nt < 4; ++nt) {
            const float o = oacc[nt][r] * inv;
            const u16 hi = f2bf(o);
            AOh[orow + nt * 16 + l15] = hi;
            AOl[orow + nt * 16 + l15] = f2bf(o - bf2f(hi));
        }
    }
}

// ---------------------------------------------------------------------------
// Host launcher
// ---------------------------------------------------------------------------
extern "C" void kernel_launch(void* const* d_in, const int* in_sizes, int n_in,
                              void* d_out, int out_size, void* d_ws,
                              size_t ws_size, hipStream_t stream)
{
    const float* hidden = (const float*)d_in[0];
    const float* sinp   = (const float*)d_in[1];
    const float* cosp   = (const float*)d_in[2];
    // d_in[3] = mask — causal, handled analytically
    const float* ln1    = (const float*)d_in[4];
    const float* ln2    = (const float*)d_in[5];
    const float* qn     = (const float*)d_in[6];
    const float* kn     = (const float*)d_in[7];
    const float* q_w    = (const float*)d_in[8];
    const float* k_w    = (const float*)d_in[9];
    const float* v_w    = (const float*)d_in[10];
    const float* o_w    = (const float*)d_in[11];
    const float* gate_w = (const float*)d_in[12];
    const float* up_w   = (const float*)d_in[13];
    const float* down_w = (const float*)d_in[14];
    float* out = (float*)d_out;

    // ---- workspace layout (116.4 MB; capacity >= 120.6 MB proven r8) ----
    char* base = (char*)d_ws;
    u16*   OTh  = (u16*)(base);                //  2 MB
    u16*   OTl  = (u16*)(base + 2097152);      //  2 MB
    u16*   GTh  = (u16*)(base + 4194304);      //  8 MB
    u16*   UTh  = (u16*)(base + 12582912);     //  8 MB
    u16*   DTh  = (u16*)(base + 20971520);     //  8 MB
    u16*   QKVT = (u16*)(base + 29360128);     //  3 MB
    u16*   Xh   = (u16*)(base + 32505856);     //  8 MB
    u16*   Qbh  = (u16*)(base + 40894464);     //  8 MB
    u16*   Qbl  = (u16*)(base + 49283072);     //  8 MB
    u16*   Kbh  = (u16*)(base + 57671680);     //  2 MB
    u16*   Kbl  = (u16*)(base + 59768832);     //  2 MB
    u16*   Vth  = (u16*)(base + 61865984);     //  2 MB
    u16*   Vtl  = (u16*)(base + 63963136);     //  2 MB
    u16*   AOh  = (u16*)(base + 66060288);     //  8 MB
    u16*   AOl  = (u16*)(base + 74448896);     //  8 MB
    u16*   FFh  = (u16*)(base + 82837504);     // 32 MB (end 116,391,936)

    // aliases (lifetime-checked):
    float* H2 = (float*)Qbh;   // 16 MB over Qbh+Qbl (Q dead post-attn)
    u16*   Yh = Kbh;           //  8 MB over Kbh..Vtl (K/V dead post-attn)
    u16*   Yl = AOh;           //  8 MB over AOh (AO dead post-o-proj)

    // 0. all weight prep, one launch
    wprep_all_kernel<<<14848, 256, 0, stream>>>(
        q_w, k_w, v_w, o_w, gate_w, up_w, down_w,
        QKVT, OTh, OTl, GTh, UTh, DTh);

    // 1. x = rmsnorm(hidden, ln1) -> bf16
    rmsnorm_split_kernel<0><<<Mrows, 256, 0, stream>>>(hidden, ln1, Xh, nullptr);

    // 2. fused qkv projection + qknorm + rope + split + V-transpose
    qkv_fused_kernel<<<dim3(12, 32), 256, 0, stream>>>(
        Xh, QKVT, qn, kn, sinp, cosp, Qbh, Qbl, Kbh, Kbl, Vth, Vtl);

    // 3. MFMA flash attention v3 (r8 revert) -> AO bf16 hi/lo
    attn_mfma_kernel<<<Bsz * Gg * (Tseq / 16), 256, 0, stream>>>(
        Qbh, Qbl, Kbh, Kbl, Vth, Vtl, AOh, AOl);

    // 4. hidden2 = hidden + attn @ o_w  (split x split)
    mfma_gemm_kernel<1, 1, 1><<<dim3(8, 32), 256, 0, stream>>>(
        AOh, AOl, OTh, OTl, hidden, H2, Mrows, Dmod, 1024);

    // 5. y = rmsnorm(hidden2, ln2) -> bf16 hi/lo
    rmsnorm_split_kernel<1><<<Mrows, 256, 0, stream>>>(H2, ln2, Yh, Yl);

    // 6. ff = silu(y@gate_w) * (y@up_w) -> FF bf16
    //    r12: 32x32x16 MFMA, 2 phases/K-step, triple-buffer unroll-3,
    //    counted vmcnt + setprio, STRENGTHENED swizzle (see comment above).
    gateup32_kernel<<<512, 512, 0, stream>>>(Yh, Yl, GTh, UTh, FFh);

    // 7. out = hidden2 + ff @ down_w
    mfma_gemm_kernel<0, 0, 1><<<dim3(8, 32), 256, 0, stream>>>(
        FFh, nullptr, DTh, nullptr, H2, out, Mrows, Dmod, 4096);
}

// Round 4
// 498.947 us; speedup vs baseline: 1.0709x; 1.0654x over previous
//
#include <hip/hip_runtime.h>
#include <hip/hip_bf16.h>

// Problem constants: B=2, T=2048, D=1024, H=16, G=4, K=64, F=4096
#define EPSF 1e-6f
constexpr int Bsz  = 2;
constexpr int Tseq = 2048;
constexpr int Dmod = 1024;
constexpr int Hh   = 16;
constexpr int Gg   = 4;
constexpr int Ff   = 4096;
constexpr int Mrows = Bsz * Tseq;          // 4096 tokens

typedef __attribute__((ext_vector_type(8))) short bf16x8;   // 8 bf16 (4 VGPRs)
typedef __attribute__((ext_vector_type(4))) float f32x4;
typedef unsigned short u16;

// RNE fp32 -> bf16 (bit pattern as u16)
__device__ inline u16 f2bf(float x) {
    union { float f; unsigned u; } v; v.f = x;
    unsigned r = v.u + 0x7fff + ((v.u >> 16) & 1);
    return (u16)(r >> 16);
}
__device__ inline float bf2f(u16 h) {
    union { unsigned u; float f; } v; v.u = ((unsigned)h) << 16; return v.f;
}

// Async global->LDS DMA, 16 B per lane (wave-uniform base + lane*16).
__device__ __forceinline__ void async_copy16(const u16* g, u16* l) {
    __builtin_amdgcn_global_load_lds(
        (const __attribute__((address_space(1))) void*)g,
        (__attribute__((address_space(3))) void*)l, 16, 0, 0);
}

// Bank-swizzle: LDS tiles [row][32] bf16 (64 B rows). Logical k-chunk q of row
// R stored at chunk q ^ ((R>>1)&3); staging fetches global chunk
// (lane&3)^((row>>1)&3) into linear dest lane*16; reads XOR the same term.
// Conflict-free ONLY for the 16x16 read geometry (16 rows x 4 quad-chunks per
// wave read) — verified r7/r10: SQ_LDS_BANK_CONFLICT = 0.
// r11/r12 lesson: the 32x32x16 read geometry (32 rows x 2 k-halves) conflicts
// (~1.05e7) under ANY chunk-XOR f — both ((R>>1)&3) and the strengthened
// f^((R>>3)&3) gave bit-identical conflict counts (slot-pairing degree is
// invariant under XOR choice for that geometry). Stick to 16x16 reads.

// ---------------------------------------------------------------------------
// ALL weight prep in ONE launch (kept from r9 — sound). 14848 blocks.
// ---------------------------------------------------------------------------
__global__ __launch_bounds__(256) void wprep_all_kernel(
    const float* __restrict__ q_w, const float* __restrict__ k_w,
    const float* __restrict__ v_w, const float* __restrict__ o_w,
    const float* __restrict__ gate_w, const float* __restrict__ up_w,
    const float* __restrict__ down_w,
    u16* __restrict__ QKVT, u16* __restrict__ OTh, u16* __restrict__ OTl,
    u16* __restrict__ GTh, u16* __restrict__ UTh, u16* __restrict__ DTh)
{
    const int bx = blockIdx.x;
    const float* W; u16* Th; u16* Tl = nullptr;
    int N, Kd, ntile, ktile, drow;
    if (bx < 1024) {
        W = q_w; N = 1024; Kd = 1024; ntile = bx & 31; ktile = bx >> 5;
        Th = QKVT; drow = ntile * 32;
    } else if (bx < 1280) {
        const int i = bx - 1024;
        W = k_w; N = 256; Kd = 1024; ntile = i & 7; ktile = i >> 3;
        Th = QKVT; drow = 1024 + ntile * 32;
    } else if (bx < 1536) {
        const int i = bx - 1280;
        W = v_w; N = 256; Kd = 1024; ntile = i & 7; ktile = i >> 3;
        Th = QKVT; drow = 1280 + ntile * 32;
    } else if (bx < 2560) {
        const int i = bx - 1536;
        W = o_w; N = 1024; Kd = 1024; ntile = i & 31; ktile = i >> 5;
        Th = OTh; Tl = OTl; drow = ntile * 32;
    } else if (bx < 6656) {
        const int i = bx - 2560;
        W = gate_w; N = 4096; Kd = 1024; ntile = i & 127; ktile = i >> 7;
        Th = GTh; drow = ntile * 32;
    } else if (bx < 10752) {
        const int i = bx - 6656;
        W = up_w; N = 4096; Kd = 1024; ntile = i & 127; ktile = i >> 7;
        Th = UTh; drow = ntile * 32;
    } else {
        const int i = bx - 10752;
        W = down_w; N = 1024; Kd = 4096; ntile = i & 31; ktile = i >> 5;
        Th = DTh; drow = ntile * 32;
    }
    const int n0 = ntile * 32, k0 = ktile * 32;

    __shared__ float tile[32][33];
    const int r = threadIdx.x >> 3, c4 = (threadIdx.x & 7) * 4;
    const float4 v = *reinterpret_cast<const float4*>(&W[(size_t)(k0 + r) * N + n0 + c4]);
    tile[r][c4 + 0] = v.x; tile[r][c4 + 1] = v.y;
    tile[r][c4 + 2] = v.z; tile[r][c4 + 3] = v.w;
    __syncthreads();
    const int nl = threadIdx.x >> 3, kq = (threadIdx.x & 7) * 4;
    float x0 = tile[kq + 0][nl], x1 = tile[kq + 1][nl];
    float x2 = tile[kq + 2][nl], x3 = tile[kq + 3][nl];
    ushort4 h;
    h.x = f2bf(x0); h.y = f2bf(x1); h.z = f2bf(x2); h.w = f2bf(x3);
    *reinterpret_cast<ushort4*>(&Th[(size_t)(drow + nl) * Kd + k0 + kq]) = h;
    if (Tl) {
        ushort4 l;
        l.x = f2bf(x0 - bf2f(h.x)); l.y = f2bf(x1 - bf2f(h.y));
        l.z = f2bf(x2 - bf2f(h.z)); l.w = f2bf(x3 - bf2f(h.w));
        *reinterpret_cast<ushort4*>(&Tl[(size_t)(drow + nl) * Kd + k0 + kq]) = l;
    }
}

// ---------------------------------------------------------------------------
// RMSNorm over D=1024 -> bf16 hi (+ optional lo). One block per token.
// ---------------------------------------------------------------------------
template <int LO>
__global__ __launch_bounds__(256) void rmsnorm_split_kernel(
    const float* __restrict__ x, const float* __restrict__ scale,
    u16* __restrict__ oh, u16* __restrict__ ol)
{
    const int row = blockIdx.x;
    const int tid = threadIdx.x;
    const float4 v = reinterpret_cast<const float4*>(x + (size_t)row * Dmod)[tid];
    float ss = v.x * v.x + v.y * v.y + v.z * v.z + v.w * v.w;
    #pragma unroll
    for (int off = 32; off; off >>= 1) ss += __shfl_xor(ss, off, 64);
    __shared__ float part[4];
    if ((tid & 63) == 0) part[tid >> 6] = ss;
    __syncthreads();
    const float tot = part[0] + part[1] + part[2] + part[3];
    const float rstd = rsqrtf(tot * (1.0f / Dmod) + EPSF);
    const float4 sc = reinterpret_cast<const float4*>(scale)[tid];
    float o0 = v.x * rstd * sc.x, o1 = v.y * rstd * sc.y;
    float o2 = v.z * rstd * sc.z, o3 = v.w * rstd * sc.w;
    ushort4 h;
    h.x = f2bf(o0); h.y = f2bf(o1); h.z = f2bf(o2); h.w = f2bf(o3);
    *reinterpret_cast<ushort4*>(&oh[(size_t)row * Dmod + tid * 4]) = h;
    if (LO) {
        ushort4 l;
        l.x = f2bf(o0 - bf2f(h.x)); l.y = f2bf(o1 - bf2f(h.y));
        l.z = f2bf(o2 - bf2f(h.z)); l.w = f2bf(o3 - bf2f(h.w));
        *reinterpret_cast<ushort4*>(&ol[(size_t)row * Dmod + tid * 4]) = l;
    }
}

// ---------------------------------------------------------------------------
// Split-bf16 MFMA GEMM, r13 PIPELINED: identical geometry, swizzle, and
// per-accumulator MFMA order as the old mfma_gemm_kernel (bitwise-same
// numerics), but triple-buffered LDS, stage(t+2) during step t, counted
// vmcnt(NI) never drained in the loop, lgkmcnt(0)+sched_barrier fence,
// setprio around the MFMA cluster. Targets the 1-wave/SIMD kernels (o-proj,
// down-proj at grid==256) where the old vmcnt(0) barrier drain had no TLP
// to hide under. Race invariants identical to r10's proven 6-issue pipeline
// (here NI=4 or 8 issues/K-step; FIFO completion per m135).
// ---------------------------------------------------------------------------
template <int NKT, int ASPLIT, int BSPLIT, int RES>
__global__ __launch_bounds__(256, 2) void mfma_gemm_pipe(
    const u16* __restrict__ Ah, const u16* __restrict__ Al,
    const u16* __restrict__ Bh, const u16* __restrict__ Bl,
    const float* __restrict__ res, float* __restrict__ C,
    int M, int N)
{
    constexpr int Kd = NKT * 32;
    constexpr int NI = 4 + 4 * ASPLIT * 0 + 2 * ASPLIT + 2 * BSPLIT; // issues/K-step
    static_assert((NKT - 2) % 3 == 0, "main loop unroll-3");

    __shared__ u16 AsH[3][128 * 32];                    // 24 KB
    __shared__ u16 BsH[3][128 * 32];                    // 24 KB
    __shared__ u16 AsL[ASPLIT ? 3 : 1][128 * 32];       // 24/8 KB
    __shared__ u16 BsL[BSPLIT ? 3 : 1][128 * 32];       // 24/8 KB

    const int tid = threadIdx.x;
    const int lane = tid & 63, wave = tid >> 6;
    const int wm = (wave >> 1) * 64, wn = (wave & 1) * 64;
    const int m0 = blockIdx.y * 128, n0 = blockIdx.x * 128;
    const int fm = lane & 15, quad = lane >> 4;
    const int fsw = (fm >> 1) & 3;
    const int fcol = (quad ^ fsw) * 8;

    f32x4 acc[4][4];
    #pragma unroll
    for (int i = 0; i < 4; ++i)
        #pragma unroll
        for (int j = 0; j < 4; ++j) acc[i][j] = (f32x4){0.f, 0.f, 0.f, 0.f};

    // staging: 256 thr * 16 B = 4 KB/issue; each 128x32 tile = 2 issues
    const int srow = tid >> 2;             // 0..63
    const int schk = tid & 3;
    const int sw   = schk ^ ((srow >> 1) & 3);   // f(srow+64)==f(srow)
    const u16* aS0 = &Ah[(size_t)(m0 + srow) * Kd + sw * 8];
    const u16* aS1 = &Ah[(size_t)(m0 + srow + 64) * Kd + sw * 8];
    const u16* bS0 = &Bh[(size_t)(n0 + srow) * Kd + sw * 8];
    const u16* bS1 = &Bh[(size_t)(n0 + srow + 64) * Kd + sw * 8];
    const u16* alS0 = ASPLIT ? &Al[(size_t)(m0 + srow) * Kd + sw * 8] : nullptr;
    const u16* alS1 = ASPLIT ? &Al[(size_t)(m0 + srow + 64) * Kd + sw * 8] : nullptr;
    const u16* blS0 = BSPLIT ? &Bl[(size_t)(n0 + srow) * Kd + sw * 8] : nullptr;
    const u16* blS1 = BSPLIT ? &Bl[(size_t)(n0 + srow + 64) * Kd + sw * 8] : nullptr;
    const int dst0 = srow * 32 + schk * 8;       // bytes = tid*16 (linear)
    const int dst1 = dst0 + 64 * 32;

#define PSTAGE(T, BUF) do {                                                  \
        async_copy16(aS0 + (T) * 32, &AsH[BUF][dst0]);                       \
        async_copy16(aS1 + (T) * 32, &AsH[BUF][dst1]);                       \
        if (ASPLIT) {                                                        \
            async_copy16(alS0 + (T) * 32, &AsL[BUF][dst0]);                  \
            async_copy16(alS1 + (T) * 32, &AsL[BUF][dst1]);                  \
        }                                                                    \
        async_copy16(bS0 + (T) * 32, &BsH[BUF][dst0]);                       \
        async_copy16(bS1 + (T) * 32, &BsH[BUF][dst1]);                       \
        if (BSPLIT) {                                                        \
            async_copy16(blS0 + (T) * 32, &BsL[BUF][dst0]);                  \
            async_copy16(blS1 + (T) * 32, &BsL[BUF][dst1]);                  \
        }                                                                    \
    } while (0)

// GATE: 1 = steady-state counted wait vmcnt(NI), 0 = drain, -1 = none.
#define PGATE(GATE) do {                                                     \
        if ((GATE) == 1) {                                                   \
            if constexpr (NI == 4)                                           \
                asm volatile("s_waitcnt vmcnt(4)" ::: "memory");             \
            else                                                             \
                asm volatile("s_waitcnt vmcnt(8)" ::: "memory");             \
        } else if ((GATE) == 0) {                                            \
            asm volatile("s_waitcnt vmcnt(0)" ::: "memory");                 \
        }                                                                    \
    } while (0)

#define PSTEP(BC, BN, T, PF, GATE) do {                                      \
    bf16x8 ah[4], bh[4], al[4], bl[4];                                       \
    _Pragma("unroll")                                                        \
    for (int t = 0; t < 4; ++t) {                                            \
        const int ra = (wm + t * 16 + fm) * 32 + fcol;                       \
        const int rb = (wn + t * 16 + fm) * 32 + fcol;                       \
        ah[t] = *reinterpret_cast<const bf16x8*>(&AsH[BC][ra]);              \
        bh[t] = *reinterpret_cast<const bf16x8*>(&BsH[BC][rb]);              \
        if (ASPLIT) al[t] = *reinterpret_cast<const bf16x8*>(&AsL[BC][ra]);  \
        if (BSPLIT) bl[t] = *reinterpret_cast<const bf16x8*>(&BsL[BC][rb]);  \
    }                                                                        \
    if (PF) PSTAGE((T) + 2, BN);                                             \
    __builtin_amdgcn_s_barrier();                                            \
    asm volatile("s_waitcnt lgkmcnt(0)" ::: "memory");                       \
    __builtin_amdgcn_sched_barrier(0);                                       \
    __builtin_amdgcn_s_setprio(1);                                           \
    _Pragma("unroll")                                                        \
    for (int mt = 0; mt < 4; ++mt)                                           \
        _Pragma("unroll")                                                    \
        for (int nt = 0; nt < 4; ++nt) {                                     \
            acc[mt][nt] = __builtin_amdgcn_mfma_f32_16x16x32_bf16(           \
                ah[mt], bh[nt], acc[mt][nt], 0, 0, 0);                       \
            if (BSPLIT)                                                      \
                acc[mt][nt] = __builtin_amdgcn_mfma_f32_16x16x32_bf16(       \
                    ah[mt], bl[nt], acc[mt][nt], 0, 0, 0);                   \
            if (ASPLIT)                                                      \
                acc[mt][nt] = __builtin_amdgcn_mfma_f32_16x16x32_bf16(       \
                    al[mt], bh[nt], acc[mt][nt], 0, 0, 0);                   \
        }                                                                    \
    __builtin_amdgcn_s_setprio(0);                                           \
    PGATE(GATE);                                                             \
    __builtin_amdgcn_s_barrier();                                            \
} while (0)

    // prologue: fill buffers 0 and 1 (2*NI in flight -> wait NI = buf0 done)
    PSTAGE(0, 0);
    PSTAGE(1, 1);
    PGATE(1);
    __builtin_amdgcn_s_barrier();

    #pragma unroll 1
    for (int t3 = 0; t3 < NKT - 2; t3 += 3) {
        PSTEP(0, 2, t3 + 0, true, 1);
        PSTEP(1, 0, t3 + 1, true, 1);
        PSTEP(2, 1, t3 + 2, true, 1);
    }
    // tail: t=NKT-2 (buf0, drain last loads), t=NKT-1 (buf1, nothing left)
    PSTEP(0, 2, NKT - 2, false, 0);
    PSTEP(1, 0, NKT - 1, false, -1);

#undef PSTEP
#undef PGATE
#undef PSTAGE

    const int cr = (lane >> 4) * 4, cn = lane & 15;
    #pragma unroll
    for (int mt = 0; mt < 4; ++mt)
        #pragma unroll
        for (int nt = 0; nt < 4; ++nt)
            #pragma unroll
            for (int r = 0; r < 4; ++r) {
                const int gm = m0 + wm + mt * 16 + cr + r;
                const int gn = n0 + wn + nt * 16 + cn;
                float v = acc[mt][nt][r];
                if (RES) v += res[(size_t)gm * N + gn];
                C[(size_t)gm * N + gn] = v;
            }
}

// ---------------------------------------------------------------------------
// Fused QKV GEMM + qk-norm + RoPE + bf16 split epilogue; V stored TRANSPOSED
// directly (kept from r9 — sound).
// ---------------------------------------------------------------------------
__global__ __launch_bounds__(256, 2) void qkv_fused_kernel(
    const u16* __restrict__ Ah, const u16* __restrict__ Bh,
    const float* __restrict__ qn, const float* __restrict__ kn,
    const float* __restrict__ sinp, const float* __restrict__ cosp,
    u16* __restrict__ Qbh, u16* __restrict__ Qbl,
    u16* __restrict__ Kbh, u16* __restrict__ Kbl,
    u16* __restrict__ Vth, u16* __restrict__ Vtl)
{
    __shared__ u16 As_h[128 * 32];
    __shared__ u16 Bs_h[128 * 32];

    const int Kd = 1024;
    const int tid = threadIdx.x;
    const int lane = tid & 63, wave = tid >> 6;
    const int wm = (wave >> 1) * 64, wn = (wave & 1) * 64;
    const int m0 = blockIdx.y * 128, n0 = blockIdx.x * 128;
    const int fm = lane & 15, quad = lane >> 4;
    const int fsw = (fm >> 1) & 3;
    const int fcol = ((quad ^ fsw) * 8);

    f32x4 acc[4][4];
    #pragma unroll
    for (int i = 0; i < 4; ++i)
        #pragma unroll
        for (int j = 0; j < 4; ++j) acc[i][j] = (f32x4){0.f, 0.f, 0.f, 0.f};

    const int lrow = lane >> 2;
    const int lchunk = lane & 3;
    const int schunk = lchunk ^ ((lrow >> 1) & 3);

    for (int k0 = 0; k0 < Kd; k0 += 32) {
        __syncthreads();
        #pragma unroll
        for (int p = 0; p < 2; ++p) {
            const int row = wave * 32 + p * 16 + lrow;
            const size_t ga = (size_t)(m0 + row) * Kd + k0 + schunk * 8;
            const size_t gb = (size_t)(n0 + row) * Kd + k0 + schunk * 8;
            const int ls = row * 32 + lchunk * 8;
            async_copy16(&Ah[ga], &As_h[ls]);
            async_copy16(&Bh[gb], &Bs_h[ls]);
        }
        __syncthreads();

        bf16x8 ah[4], bh[4];
        #pragma unroll
        for (int t = 0; t < 4; ++t) {
            ah[t] = *reinterpret_cast<const bf16x8*>(&As_h[(wm + t * 16 + fm) * 32 + fcol]);
            bh[t] = *reinterpret_cast<const bf16x8*>(&Bs_h[(wn + t * 16 + fm) * 32 + fcol]);
        }
        #pragma unroll
        for (int mt = 0; mt < 4; ++mt)
            #pragma unroll
            for (int nt = 0; nt < 4; ++nt)
                acc[mt][nt] = __builtin_amdgcn_mfma_f32_16x16x32_bf16(
                    ah[mt], bh[nt], acc[mt][nt], 0, 0, 0);
    }

    const int gn0 = n0 + wn;          // wave col base, 64-aligned
    const int l15 = lane & 15;

    if (gn0 < 1280) {
        // ---- Q or K: per-head RMSNorm + RoPE + split ----
        const bool isQ = (gn0 < 1024);
        const float* nsc = isQ ? qn : kn;
        const float osc = isQ ? 0.125f : 1.0f;
        u16* __restrict__ oh = isQ ? Qbh : Kbh;
        u16* __restrict__ ol = isQ ? Qbl : Kbl;
        const int rowstride = isQ ? 1024 : 256;
        const int colbase = isQ ? gn0 : gn0 - 1024;
        float sc[4];
        #pragma unroll
        for (int nt = 0; nt < 4; ++nt) sc[nt] = nsc[nt * 16 + l15];

        #pragma unroll
        for (int mt = 0; mt < 4; ++mt)
            #pragma unroll
            for (int r = 0; r < 4; ++r) {
                const int bt = m0 + wm + mt * 16 + quad * 4 + r;
                float v[4];
                #pragma unroll
                for (int nt = 0; nt < 4; ++nt) v[nt] = acc[mt][nt][r];
                float ss = v[0] * v[0] + v[1] * v[1] + v[2] * v[2] + v[3] * v[3];
                #pragma unroll
                for (int off = 1; off < 16; off <<= 1)
                    ss += __shfl_xor(ss, off, 16);
                const float rstd = rsqrtf(ss * (1.0f / 64.0f) + EPSF);
                float nv[4];
                #pragma unroll
                for (int nt = 0; nt < 4; ++nt) nv[nt] = v[nt] * rstd * sc[nt];
                const float s0 = sinp[bt * 32 + l15];
                const float c0 = cosp[bt * 32 + l15];
                const float s1 = sinp[bt * 32 + 16 + l15];
                const float c1 = cosp[bt * 32 + 16 + l15];
                float o[4];
                o[0] = (nv[0] * c0 - nv[2] * s0) * osc;
                o[1] = (nv[1] * c1 - nv[3] * s1) * osc;
                o[2] = (nv[2] * c0 + nv[0] * s0) * osc;
                o[3] = (nv[3] * c1 + nv[1] * s1) * osc;
                #pragma unroll
                for (int nt = 0; nt < 4; ++nt) {
                    const size_t off = (size_t)bt * rowstride + colbase + nt * 16 + l15;
                    const u16 hi = f2bf(o[nt]);
                    oh[off] = hi;
                    ol[off] = f2bf(o[nt] - bf2f(hi));
                }
            }
    } else {
        // ---- V: bf16 split, stored transposed: Vt[(b*4+g)*64+d][t] ----
        const int g = (gn0 - 1280) >> 6;
        const int b = (m0 + wm) >> 11;
        const int tb = ((m0 + wm) & 2047) + quad * 4;
        #pragma unroll
        for (int mt = 0; mt < 4; ++mt)
            #pragma unroll
            for (int nt = 0; nt < 4; ++nt) {
                const float v0 = acc[mt][nt][0], v1 = acc[mt][nt][1];
                const float v2 = acc[mt][nt][2], v3 = acc[mt][nt][3];
                ushort4 hv, lv;
                hv.x = f2bf(v0); hv.y = f2bf(v1); hv.z = f2bf(v2); hv.w = f2bf(v3);
                lv.x = f2bf(v0 - bf2f(hv.x)); lv.y = f2bf(v1 - bf2f(hv.y));
                lv.z = f2bf(v2 - bf2f(hv.z)); lv.w = f2bf(v3 - bf2f(hv.w));
                const size_t off =
                    ((size_t)((b * 4 + g) * 64 + nt * 16 + l15)) * Tseq + tb + mt * 16;
                *reinterpret_cast<ushort4*>(&Vth[off]) = hv;
                *reinterpret_cast<ushort4*>(&Vtl[off]) = lv;
            }
    }
}

// ---------------------------------------------------------------------------
// Fused gate/up GEMM — EXACT r10 revert (256x128 tile, 512 thr, 16x16 MFMA,
// 4 phases/K-step, triple-buffer, counted vmcnt(6), setprio). 133 us,
// SQ_LDS_BANK_CONFLICT = 0. The 32x32 variants (r11/r12) conflicted
// intrinsically — see swizzle note at top.
// ---------------------------------------------------------------------------
#define GU_PHASE_SYNC()                                       \
    __builtin_amdgcn_s_barrier();                             \
    asm volatile("s_waitcnt lgkmcnt(0)" ::: "memory");        \
    __builtin_amdgcn_sched_barrier(0)

#define GU_MFMA4(MBASE, AF)                                                      \
    _Pragma("unroll")                                                            \
    for (int mf = 0; mf < 4; ++mf) {                                             \
        accg[(MBASE) + mf][0] = __builtin_amdgcn_mfma_f32_16x16x32_bf16(         \
            AF[mf], bgf[0], accg[(MBASE) + mf][0], 0, 0, 0);                     \
        accu[(MBASE) + mf][0] = __builtin_amdgcn_mfma_f32_16x16x32_bf16(         \
            AF[mf], buf2[0], accu[(MBASE) + mf][0], 0, 0, 0);                    \
        accg[(MBASE) + mf][1] = __builtin_amdgcn_mfma_f32_16x16x32_bf16(         \
            AF[mf], bgf[1], accg[(MBASE) + mf][1], 0, 0, 0);                     \
        accu[(MBASE) + mf][1] = __builtin_amdgcn_mfma_f32_16x16x32_bf16(         \
            AF[mf], buf2[1], accu[(MBASE) + mf][1], 0, 0, 0);                    \
    }

__global__ __launch_bounds__(512, 2) void gateup8_kernel(
    const u16* __restrict__ Yh, const u16* __restrict__ Yl,
    const u16* __restrict__ Gw, const u16* __restrict__ Uw,
    u16* __restrict__ FF)
{
    constexpr int NK = 32;                 // K=1024 / 32
    __shared__ u16 AsH[3][256 * 32];       // 48 KB
    __shared__ u16 AsL[3][256 * 32];       // 48 KB
    __shared__ u16 Gs[3][128 * 32];        // 24 KB
    __shared__ u16 Us[3][128 * 32];        // 24 KB  -> 144 KB total, 1 blk/CU

    const int tid  = threadIdx.x;
    const int lane = tid & 63;
    const int wave = tid >> 6;
    const int wave_m = wave >> 2;          // 0..1  -> A rows wave_m*128..+127
    const int wave_n = wave & 3;           // 0..3  -> B rows wave_n*32..+31

    // XCD-aware bijective swizzle: 512 wgs = 8 xcd * 64. Per XCD: 4 n-tiles
    // (gate+up panel 2 MB -> L2-resident), consecutive idx share the m-tile.
    const int wg  = blockIdx.x;
    const int xcd = wg & 7;
    const int idx = wg >> 3;               // 0..63
    const int ntile = xcd * 4 + (idx & 3); // 0..31
    const int mtile = idx >> 2;            // 0..15
    const int m0 = mtile * 256, n0 = ntile * 128;

    const int fm = lane & 15, quad = lane >> 4;
    const int fsw = (fm >> 1) & 3;
    const int fcol = (quad ^ fsw) * 8;

    f32x4 accg[8][2], accu[8][2];
    #pragma unroll
    for (int i = 0; i < 8; ++i)
        #pragma unroll
        for (int j = 0; j < 2; ++j) {
            accg[i][j] = (f32x4){0.f, 0.f, 0.f, 0.f};
            accu[i][j] = (f32x4){0.f, 0.f, 0.f, 0.f};
        }

    // ---- staging constants (512 thr * 16 B = 8 KB per issue) ----
    const int srow = tid >> 2;             // 0..127
    const int schk = tid & 3;
    const int sw   = schk ^ ((srow >> 1) & 3);   // same for srow+128 (128%4==0)
    const u16* aSrc0 = &Yh[(size_t)(m0 + srow) * 1024 + sw * 8];
    const u16* aSrc1 = &Yh[(size_t)(m0 + srow + 128) * 1024 + sw * 8];
    const u16* lSrc0 = &Yl[(size_t)(m0 + srow) * 1024 + sw * 8];
    const u16* lSrc1 = &Yl[(size_t)(m0 + srow + 128) * 1024 + sw * 8];
    const u16* gSrc  = &Gw[(size_t)(n0 + srow) * 1024 + sw * 8];
    const u16* uSrc  = &Uw[(size_t)(n0 + srow) * 1024 + sw * 8];
    const int aDst0 = srow * 32 + schk * 8;      // bytes = tid*16 (linear)
    const int aDst1 = aDst0 + 128 * 32;

#define STAGE_AH(T, BUF) do {                                  \
        async_copy16(aSrc0 + (T) * 32, &AsH[BUF][aDst0]);      \
        async_copy16(aSrc1 + (T) * 32, &AsH[BUF][aDst1]); } while (0)
#define STAGE_AL(T, BUF) do {                                  \
        async_copy16(lSrc0 + (T) * 32, &AsL[BUF][aDst0]);      \
        async_copy16(lSrc1 + (T) * 32, &AsL[BUF][aDst1]); } while (0)
#define STAGE_B(T, BUF) do {                                   \
        async_copy16(gSrc + (T) * 32, &Gs[BUF][aDst0]);        \
        async_copy16(uSrc + (T) * 32, &Us[BUF][aDst0]); } while (0)

    // ---- fragment read offsets (u16 units) ----
    int raOff[8], rbOff[2];
    #pragma unroll
    for (int mf = 0; mf < 8; ++mf)
        raOff[mf] = (wave_m * 128 + mf * 16 + fm) * 32 + fcol;
    #pragma unroll
    for (int nf = 0; nf < 2; ++nf)
        rbOff[nf] = (wave_n * 32 + nf * 16 + fm) * 32 + fcol;

    // ---- prologue: fill buffers 0 and 1 (12 loads in flight -> wait 6) ----
    STAGE_AH(0, 0); STAGE_AL(0, 0); STAGE_B(0, 0);
    STAGE_AH(1, 1); STAGE_AL(1, 1); STAGE_B(1, 1);
    asm volatile("s_waitcnt vmcnt(6)" ::: "memory");
    __builtin_amdgcn_s_barrier();

    int bcur = 0, bnxt = 2;
    #pragma unroll 1
    for (int t = 0; t < NK; ++t) {
        const bool pf = (t + 2 < NK);
        bf16x8 bgf[2], buf2[2];

        // ---- phase 0: B frags + A-hi m0-3 ; stage A-hi(t+2) ----
        {
            #pragma unroll
            for (int nf = 0; nf < 2; ++nf) {
                bgf[nf]  = *reinterpret_cast<const bf16x8*>(&Gs[bcur][rbOff[nf]]);
                buf2[nf] = *reinterpret_cast<const bf16x8*>(&Us[bcur][rbOff[nf]]);
            }
            bf16x8 af[4];
            #pragma unroll
            for (int mf = 0; mf < 4; ++mf)
                af[mf] = *reinterpret_cast<const bf16x8*>(&AsH[bcur][raOff[mf]]);
            if (pf) STAGE_AH(t + 2, bnxt);
            GU_PHASE_SYNC();
            __builtin_amdgcn_s_setprio(1);
            GU_MFMA4(0, af);
            __builtin_amdgcn_s_setprio(0);
            __builtin_amdgcn_s_barrier();
        }
        // ---- phase 1: A-hi m4-7 ; stage A-lo(t+2) ----
        {
            bf16x8 af[4];
            #pragma unroll
            for (int mf = 0; mf < 4; ++mf)
                af[mf] = *reinterpret_cast<const bf16x8*>(&AsH[bcur][raOff[mf + 4]]);
            if (pf) STAGE_AL(t + 2, bnxt);
            GU_PHASE_SYNC();
            __builtin_amdgcn_s_setprio(1);
            GU_MFMA4(4, af);
            __builtin_amdgcn_s_setprio(0);
            __builtin_amdgcn_s_barrier();
        }
        // ---- phase 2: A-lo m0-3 ; stage B(t+2) ----
        {
            bf16x8 af[4];
            #pragma unroll
            for (int mf = 0; mf < 4; ++mf)
                af[mf] = *reinterpret_cast<const bf16x8*>(&AsL[bcur][raOff[mf]]);
            if (pf) STAGE_B(t + 2, bnxt);
            GU_PHASE_SYNC();
            __builtin_amdgcn_s_setprio(1);
            GU_MFMA4(0, af);
            __builtin_amdgcn_s_setprio(0);
            __builtin_amdgcn_s_barrier();
        }
        // ---- phase 3: A-lo m4-7 ; counted vmcnt, never 0 until the tail ----
        {
            bf16x8 af[4];
            #pragma unroll
            for (int mf = 0; mf < 4; ++mf)
                af[mf] = *reinterpret_cast<const bf16x8*>(&AsL[bcur][raOff[mf + 4]]);
            GU_PHASE_SYNC();
            __builtin_amdgcn_s_setprio(1);
            GU_MFMA4(4, af);
            __builtin_amdgcn_s_setprio(0);
            if (t + 2 < NK) {
                asm volatile("s_waitcnt vmcnt(6)" ::: "memory");
            } else if (t + 1 < NK) {
                asm volatile("s_waitcnt vmcnt(0)" ::: "memory");
            }
            __builtin_amdgcn_s_barrier();
        }

        bcur = (bcur == 2) ? 0 : bcur + 1;
        bnxt = (bnxt == 2) ? 0 : bnxt + 1;
    }
#undef STAGE_AH
#undef STAGE_AL
#undef STAGE_B

    // ---- epilogue: silu(g)*u -> bf16 ----
    const int cr = quad * 4;
    #pragma unroll
    for (int mf = 0; mf < 8; ++mf)
        #pragma unroll
        for (int nf = 0; nf < 2; ++nf)
            #pragma unroll
            for (int r = 0; r < 4; ++r) {
                const int gm = m0 + wave_m * 128 + mf * 16 + cr + r;
                const int gn = n0 + wave_n * 32 + nf * 16 + fm;
                const float g = accg[mf][nf][r];
                const float ff = (g / (1.0f + __expf(-g))) * accu[mf][nf][r];
                FF[(size_t)gm * Ff + gn] = f2bf(ff);
            }
}

// ---------------------------------------------------------------------------
// MFMA flash attention v3 (EXACT r8 revert — one 16-row window per block).
// ---------------------------------------------------------------------------
__global__ __launch_bounds__(256) void attn_mfma_kernel(
    const u16* __restrict__ Qh, const u16* __restrict__ Ql,
    const u16* __restrict__ Kh, const u16* __restrict__ Kl,
    const u16* __restrict__ Vth, const u16* __restrict__ Vtl,
    u16* __restrict__ AOh, u16* __restrict__ AOl)
{
    __shared__ u16 KsH[64 * 72];
    __shared__ u16 KsL[64 * 72];
    __shared__ u16 VsH[64 * 72];
    __shared__ u16 VsL[64 * 72];
    __shared__ u16 Ps[4][16 * 72];

    const int tid = threadIdx.x;
    const int wave = tid >> 6, lane = tid & 63;
    const int l15 = lane & 15, quad = lane >> 4;

    const int bg = blockIdx.x & 7;
    const int b = bg >> 2, g = bg & 3;
    const int win = 127 - (blockIdx.x >> 3);
    const int t0 = win * 16;
    const int h = g * 4 + wave;

    bf16x8 qh[2], ql[2];
    {
        const size_t qrow = (size_t)(b * Tseq + t0 + l15) * 1024 + h * 64;
        #pragma unroll
        for (int ks = 0; ks < 2; ++ks) {
            qh[ks] = *reinterpret_cast<const bf16x8*>(&Qh[qrow + ks * 32 + quad * 8]);
            ql[ks] = *reinterpret_cast<const bf16x8*>(&Ql[qrow + ks * 32 + quad * 8]);
        }
    }

    const int srow = tid >> 2;
    const int scol = (tid & 3) * 16;
    const size_t kgb = (size_t)(b * Tseq) * 256 + g * 64 + scol;
    const size_t vgb = (size_t)(bg * 64 + srow) * Tseq + scol;

    const int nit = t0 / 64 + 1;

    uint4 ck0, ck1, cl0, cl1, cv0, cv1, cw0, cw1;
    {
        const size_t ka = kgb + (size_t)srow * 256;
        ck0 = *reinterpret_cast<const uint4*>(&Kh[ka]);
        ck1 = *reinterpret_cast<const uint4*>(&Kh[ka + 8]);
        cl0 = *reinterpret_cast<const uint4*>(&Kl[ka]);
        cl1 = *reinterpret_cast<const uint4*>(&Kl[ka + 8]);
        cv0 = *reinterpret_cast<const uint4*>(&Vth[vgb]);
        cv1 = *reinterpret_cast<const uint4*>(&Vth[vgb + 8]);
        cw0 = *reinterpret_cast<const uint4*>(&Vtl[vgb]);
        cw1 = *reinterpret_cast<const uint4*>(&Vtl[vgb + 8]);
    }

    f32x4 oacc[4];
    #pragma unroll
    for (int nt = 0; nt < 4; ++nt) oacc[nt] = (f32x4){0.f, 0.f, 0.f, 0.f};
    float m_r[4], l_r[4];
    #pragma unroll
    for (int r = 0; r < 4; ++r) { m_r[r] = -1e30f; l_r[r] = 0.0f; }

    u16* psw = &Ps[wave][0];
    const int lb = srow * 72 + scol;

    for (int it = 0; it < nit; ++it) {
        const int s0 = it * 64;
        const bool diag = (it == nit - 1);

        __syncthreads();
        *reinterpret_cast<uint4*>(&KsH[lb])     = ck0;
        *reinterpret_cast<uint4*>(&KsH[lb + 8]) = ck1;
        *reinterpret_cast<uint4*>(&KsL[lb])     = cl0;
        *reinterpret_cast<uint4*>(&KsL[lb + 8]) = cl1;
        *reinterpret_cast<uint4*>(&VsH[lb])     = cv0;
        *reinterpret_cast<uint4*>(&VsH[lb + 8]) = cv1;
        *reinterpret_cast<uint4*>(&VsL[lb])     = cw0;
        *reinterpret_cast<uint4*>(&VsL[lb + 8]) = cw1;
        if (it + 1 < nit) {
            const size_t ka = kgb + (size_t)(s0 + 64 + srow) * 256;
            ck0 = *reinterpret_cast<const uint4*>(&Kh[ka]);
            ck1 = *reinterpret_cast<const uint4*>(&Kh[ka + 8]);
            cl0 = *reinterpret_cast<const uint4*>(&Kl[ka]);
            cl1 = *reinterpret_cast<const uint4*>(&Kl[ka + 8]);
            const size_t va = vgb + s0 + 64;
            cv0 = *reinterpret_cast<const uint4*>(&Vth[va]);
            cv1 = *reinterpret_cast<const uint4*>(&Vth[va + 8]);
            cw0 = *reinterpret_cast<const uint4*>(&Vtl[va]);
            cw1 = *reinterpret_cast<const uint4*>(&Vtl[va + 8]);
        }
        __syncthreads();

        f32x4 sacc[4];
        #pragma unroll
        for (int nt = 0; nt < 4; ++nt) sacc[nt] = (f32x4){0.f, 0.f, 0.f, 0.f};

        #pragma unroll
        for (int ks = 0; ks < 2; ++ks) {
            bf16x8 kfh[4], kfl[4];
            #pragma unroll
            for (int nt = 0; nt < 4; ++nt) {
                const int a = (nt * 16 + l15) * 72 + ks * 32 + quad * 8;
                kfh[nt] = *reinterpret_cast<const bf16x8*>(&KsH[a]);
                kfl[nt] = *reinterpret_cast<const bf16x8*>(&KsL[a]);
            }
            #pragma unroll
            for (int nt = 0; nt < 4; ++nt) {
                sacc[nt] = __builtin_amdgcn_mfma_f32_16x16x32_bf16(qh[ks], kfh[nt], sacc[nt], 0, 0, 0);
                sacc[nt] = __builtin_amdgcn_mfma_f32_16x16x32_bf16(ql[ks], kfh[nt], sacc[nt], 0, 0, 0);
                sacc[nt] = __builtin_amdgcn_mfma_f32_16x16x32_bf16(qh[ks], kfl[nt], sacc[nt], 0, 0, 0);
            }
        }

        if (diag) {
            #pragma unroll
            for (int nt = 0; nt < 4; ++nt) {
                const int sg = s0 + nt * 16 + l15;
                #pragma unroll
                for (int r = 0; r < 4; ++r)
                    if (sg > t0 + quad * 4 + r) sacc[nt][r] = -1e30f;
            }
        }

        #pragma unroll
        for (int r = 0; r < 4; ++r) {
            float mx = fmaxf(fmaxf(sacc[0][r], sacc[1][r]),
                             fmaxf(sacc[2][r], sacc[3][r]));
            #pragma unroll
            for (int off = 1; off < 16; off <<= 1)
                mx = fmaxf(mx, __shfl_xor(mx, off, 16));
            const float mnew = fmaxf(m_r[r], mx);
            const float alpha = __expf(m_r[r] - mnew);
            m_r[r] = mnew;

            float rs = 0.0f;
            #pragma unroll
            for (int nt = 0; nt < 4; ++nt) {
                const float p = __expf(sacc[nt][r] - mnew);
                sacc[nt][r] = p;
                rs += p;
            }
            #pragma unroll
            for (int off = 1; off < 16; off <<= 1)
                rs += __shfl_xor(rs, off, 16);
            l_r[r] = l_r[r] * alpha + rs;
            #pragma unroll
            for (int nt = 0; nt < 4; ++nt) oacc[nt][r] *= alpha;
            #pragma unroll
            for (int nt = 0; nt < 4; ++nt)
                psw[(quad * 4 + r) * 72 + nt * 16 + l15] = f2bf(sacc[nt][r]);
        }

        #pragma unroll
        for (int ks = 0; ks < 2; ++ks) {
            const bf16x8 pa = *reinterpret_cast<const bf16x8*>(
                &psw[l15 * 72 + ks * 32 + quad * 8]);
            bf16x8 vfh[4], vfl[4];
            #pragma unroll
            for (int nt = 0; nt < 4; ++nt) {
                const int a = (nt * 16 + l15) * 72 + ks * 32 + quad * 8;
                vfh[nt] = *reinterpret_cast<const bf16x8*>(&VsH[a]);
                vfl[nt] = *reinterpret_cast<const bf16x8*>(&VsL[a]);
            }
            #pragma unroll
            for (int nt = 0; nt < 4; ++nt) {
                oacc[nt] = __builtin_amdgcn_mfma_f32_16x16x32_bf16(pa, vfh[nt], oacc[nt], 0, 0, 0);
                oacc[nt] = __builtin_amdgcn_mfma_f32_16x16x32_bf16(pa, vfl[nt], oacc[nt], 0, 0, 0);
            }
        }
    }

    #pragma unroll
    for (int r = 0; r < 4; ++r) {
        const float inv = 1.0f / l_r[r];
        const size_t orow = (size_t)(b * Tseq + t0 + quad * 4 + r) * 1024 + h * 64;
        #pragma unroll
        for (int nt = 0; nt < 4; ++nt) {
            const float o = oacc[nt][r] * inv;
            const u16 hi = f2bf(o);
            AOh[orow + nt * 16 + l15] = hi;
            AOl[orow + nt * 16 + l15] = f2bf(o - bf2f(hi));
        }
    }
}

// ---------------------------------------------------------------------------
// Host launcher
// ---------------------------------------------------------------------------
extern "C" void kernel_launch(void* const* d_in, const int* in_sizes, int n_in,
                              void* d_out, int out_size, void* d_ws,
                              size_t ws_size, hipStream_t stream)
{
    const float* hidden = (const float*)d_in[0];
    const float* sinp   = (const float*)d_in[1];
    const float* cosp   = (const float*)d_in[2];
    // d_in[3] = mask — causal, handled analytically
    const float* ln1    = (const float*)d_in[4];
    const float* ln2    = (const float*)d_in[5];
    const float* qn     = (const float*)d_in[6];
    const float* kn     = (const float*)d_in[7];
    const float* q_w    = (const float*)d_in[8];
    const float* k_w    = (const float*)d_in[9];
    const float* v_w    = (const float*)d_in[10];
    const float* o_w    = (const float*)d_in[11];
    const float* gate_w = (const float*)d_in[12];
    const float* up_w   = (const float*)d_in[13];
    const float* down_w = (const float*)d_in[14];
    float* out = (float*)d_out;

    // ---- workspace layout (116.4 MB; capacity >= 120.6 MB proven r8) ----
    char* base = (char*)d_ws;
    u16*   OTh  = (u16*)(base);                //  2 MB
    u16*   OTl  = (u16*)(base + 2097152);      //  2 MB
    u16*   GTh  = (u16*)(base + 4194304);      //  8 MB
    u16*   UTh  = (u16*)(base + 12582912);     //  8 MB
    u16*   DTh  = (u16*)(base + 20971520);     //  8 MB
    u16*   QKVT = (u16*)(base + 29360128);     //  3 MB
    u16*   Xh   = (u16*)(base + 32505856);     //  8 MB
    u16*   Qbh  = (u16*)(base + 40894464);     //  8 MB
    u16*   Qbl  = (u16*)(base + 49283072);     //  8 MB
    u16*   Kbh  = (u16*)(base + 57671680);     //  2 MB
    u16*   Kbl  = (u16*)(base + 59768832);     //  2 MB
    u16*   Vth  = (u16*)(base + 61865984);     //  2 MB
    u16*   Vtl  = (u16*)(base + 63963136);     //  2 MB
    u16*   AOh  = (u16*)(base + 66060288);     //  8 MB
    u16*   AOl  = (u16*)(base + 74448896);     //  8 MB
    u16*   FFh  = (u16*)(base + 82837504);     // 32 MB (end 116,391,936)

    // aliases (lifetime-checked):
    float* H2 = (float*)Qbh;   // 16 MB over Qbh+Qbl (Q dead post-attn)
    u16*   Yh = Kbh;           //  8 MB over Kbh..Vtl (K/V dead post-attn)
    u16*   Yl = AOh;           //  8 MB over AOh (AO dead post-o-proj)

    // 0. all weight prep, one launch
    wprep_all_kernel<<<14848, 256, 0, stream>>>(
        q_w, k_w, v_w, o_w, gate_w, up_w, down_w,
        QKVT, OTh, OTl, GTh, UTh, DTh);

    // 1. x = rmsnorm(hidden, ln1) -> bf16
    rmsnorm_split_kernel<0><<<Mrows, 256, 0, stream>>>(hidden, ln1, Xh, nullptr);

    // 2. fused qkv projection + qknorm + rope + split + V-transpose
    qkv_fused_kernel<<<dim3(12, 32), 256, 0, stream>>>(
        Xh, QKVT, qn, kn, sinp, cosp, Qbh, Qbl, Kbh, Kbl, Vth, Vtl);

    // 3. MFMA flash attention v3 (r8 revert) -> AO bf16 hi/lo
    attn_mfma_kernel<<<Bsz * Gg * (Tseq / 16), 256, 0, stream>>>(
        Qbh, Qbl, Kbh, Kbl, Vth, Vtl, AOh, AOl);

    // 4. hidden2 = hidden + attn @ o_w  (split x split) — r13 pipelined
    mfma_gemm_pipe<32, 1, 1, 1><<<dim3(8, 32), 256, 0, stream>>>(
        AOh, AOl, OTh, OTl, hidden, H2, Mrows, Dmod);

    // 5. y = rmsnorm(hidden2, ln2) -> bf16 hi/lo
    rmsnorm_split_kernel<1><<<Mrows, 256, 0, stream>>>(H2, ln2, Yh, Yl);

    // 6. ff = silu(y@gate_w) * (y@up_w) -> FF bf16 (r10 revert — 133 us,
    //    conflicts 0)
    gateup8_kernel<<<512, 512, 0, stream>>>(Yh, Yl, GTh, UTh, FFh);

    // 7. out = hidden2 + ff @ down_w — r13 pipelined
    mfma_gemm_pipe<128, 0, 0, 1><<<dim3(8, 32), 256, 0, stream>>>(
        FFh, nullptr, DTh, nullptr, H2, out, Mrows, Dmod);
}

// Round 5
// 496.228 us; speedup vs baseline: 1.0768x; 1.0055x over previous
//
#include <hip/hip_runtime.h>
#include <hip/hip_bf16.h>

// Problem constants: B=2, T=2048, D=1024, H=16, G=4, K=64, F=4096
#define EPSF 1e-6f
constexpr int Bsz  = 2;
constexpr int Tseq = 2048;
constexpr int Dmod = 1024;
constexpr int Hh   = 16;
constexpr int Gg   = 4;
constexpr int Ff   = 4096;
constexpr int Mrows = Bsz * Tseq;          // 4096 tokens

typedef __attribute__((ext_vector_type(8))) short bf16x8;   // 8 bf16 (4 VGPRs)
typedef __attribute__((ext_vector_type(4))) float f32x4;
typedef unsigned short u16;

// RNE fp32 -> bf16 (bit pattern as u16)
__device__ inline u16 f2bf(float x) {
    union { float f; unsigned u; } v; v.f = x;
    unsigned r = v.u + 0x7fff + ((v.u >> 16) & 1);
    return (u16)(r >> 16);
}
__device__ inline float bf2f(u16 h) {
    union { unsigned u; float f; } v; v.u = ((unsigned)h) << 16; return v.f;
}

// Async global->LDS DMA, 16 B per lane (wave-uniform base + lane*16).
__device__ __forceinline__ void async_copy16(const u16* g, u16* l) {
    __builtin_amdgcn_global_load_lds(
        (const __attribute__((address_space(1))) void*)g,
        (__attribute__((address_space(3))) void*)l, 16, 0, 0);
}

// Bank-swizzle: LDS tiles [row][32] bf16 (64 B rows). Logical k-chunk q of row
// R stored at chunk q ^ ((R>>1)&3); staging fetches global chunk
// (lane&3)^((row>>1)&3) into linear dest lane*16; reads XOR the same term.
// Conflict-free ONLY for the 16x16 read geometry (16 rows x 4 quad-chunks per
// wave read) — verified r7/r10: SQ_LDS_BANK_CONFLICT = 0. The 32x32 read
// geometry conflicts under ANY chunk-XOR (r11/r12, bit-identical 1.05e7).
//
// r14 model (from r13 counters): gateup is LDS-BANDWIDTH-bound — 208 KB
// LDS traffic per K-step per CU ≈ 2450 cyc at 85 B/cyc vs 4950 measured.
// Fix: (4 wave_m x 2 wave_n) wave tiling cuts traffic to 176 KB (-15%)
// while keeping the conflict-free 16x16 read geometry.

// ---------------------------------------------------------------------------
// ALL weight prep in ONE launch (kept from r9 — sound). 14848 blocks.
// ---------------------------------------------------------------------------
__global__ __launch_bounds__(256) void wprep_all_kernel(
    const float* __restrict__ q_w, const float* __restrict__ k_w,
    const float* __restrict__ v_w, const float* __restrict__ o_w,
    const float* __restrict__ gate_w, const float* __restrict__ up_w,
    const float* __restrict__ down_w,
    u16* __restrict__ QKVT, u16* __restrict__ OTh, u16* __restrict__ OTl,
    u16* __restrict__ GTh, u16* __restrict__ UTh, u16* __restrict__ DTh)
{
    const int bx = blockIdx.x;
    const float* W; u16* Th; u16* Tl = nullptr;
    int N, Kd, ntile, ktile, drow;
    if (bx < 1024) {
        W = q_w; N = 1024; Kd = 1024; ntile = bx & 31; ktile = bx >> 5;
        Th = QKVT; drow = ntile * 32;
    } else if (bx < 1280) {
        const int i = bx - 1024;
        W = k_w; N = 256; Kd = 1024; ntile = i & 7; ktile = i >> 3;
        Th = QKVT; drow = 1024 + ntile * 32;
    } else if (bx < 1536) {
        const int i = bx - 1280;
        W = v_w; N = 256; Kd = 1024; ntile = i & 7; ktile = i >> 3;
        Th = QKVT; drow = 1280 + ntile * 32;
    } else if (bx < 2560) {
        const int i = bx - 1536;
        W = o_w; N = 1024; Kd = 1024; ntile = i & 31; ktile = i >> 5;
        Th = OTh; Tl = OTl; drow = ntile * 32;
    } else if (bx < 6656) {
        const int i = bx - 2560;
        W = gate_w; N = 4096; Kd = 1024; ntile = i & 127; ktile = i >> 7;
        Th = GTh; drow = ntile * 32;
    } else if (bx < 10752) {
        const int i = bx - 6656;
        W = up_w; N = 4096; Kd = 1024; ntile = i & 127; ktile = i >> 7;
        Th = UTh; drow = ntile * 32;
    } else {
        const int i = bx - 10752;
        W = down_w; N = 1024; Kd = 4096; ntile = i & 31; ktile = i >> 5;
        Th = DTh; drow = ntile * 32;
    }
    const int n0 = ntile * 32, k0 = ktile * 32;

    __shared__ float tile[32][33];
    const int r = threadIdx.x >> 3, c4 = (threadIdx.x & 7) * 4;
    const float4 v = *reinterpret_cast<const float4*>(&W[(size_t)(k0 + r) * N + n0 + c4]);
    tile[r][c4 + 0] = v.x; tile[r][c4 + 1] = v.y;
    tile[r][c4 + 2] = v.z; tile[r][c4 + 3] = v.w;
    __syncthreads();
    const int nl = threadIdx.x >> 3, kq = (threadIdx.x & 7) * 4;
    float x0 = tile[kq + 0][nl], x1 = tile[kq + 1][nl];
    float x2 = tile[kq + 2][nl], x3 = tile[kq + 3][nl];
    ushort4 h;
    h.x = f2bf(x0); h.y = f2bf(x1); h.z = f2bf(x2); h.w = f2bf(x3);
    *reinterpret_cast<ushort4*>(&Th[(size_t)(drow + nl) * Kd + k0 + kq]) = h;
    if (Tl) {
        ushort4 l;
        l.x = f2bf(x0 - bf2f(h.x)); l.y = f2bf(x1 - bf2f(h.y));
        l.z = f2bf(x2 - bf2f(h.z)); l.w = f2bf(x3 - bf2f(h.w));
        *reinterpret_cast<ushort4*>(&Tl[(size_t)(drow + nl) * Kd + k0 + kq]) = l;
    }
}

// ---------------------------------------------------------------------------
// RMSNorm over D=1024 -> bf16 hi (+ optional lo). One block per token.
// ---------------------------------------------------------------------------
template <int LO>
__global__ __launch_bounds__(256) void rmsnorm_split_kernel(
    const float* __restrict__ x, const float* __restrict__ scale,
    u16* __restrict__ oh, u16* __restrict__ ol)
{
    const int row = blockIdx.x;
    const int tid = threadIdx.x;
    const float4 v = reinterpret_cast<const float4*>(x + (size_t)row * Dmod)[tid];
    float ss = v.x * v.x + v.y * v.y + v.z * v.z + v.w * v.w;
    #pragma unroll
    for (int off = 32; off; off >>= 1) ss += __shfl_xor(ss, off, 64);
    __shared__ float part[4];
    if ((tid & 63) == 0) part[tid >> 6] = ss;
    __syncthreads();
    const float tot = part[0] + part[1] + part[2] + part[3];
    const float rstd = rsqrtf(tot * (1.0f / Dmod) + EPSF);
    const float4 sc = reinterpret_cast<const float4*>(scale)[tid];
    float o0 = v.x * rstd * sc.x, o1 = v.y * rstd * sc.y;
    float o2 = v.z * rstd * sc.z, o3 = v.w * rstd * sc.w;
    ushort4 h;
    h.x = f2bf(o0); h.y = f2bf(o1); h.z = f2bf(o2); h.w = f2bf(o3);
    *reinterpret_cast<ushort4*>(&oh[(size_t)row * Dmod + tid * 4]) = h;
    if (LO) {
        ushort4 l;
        l.x = f2bf(o0 - bf2f(h.x)); l.y = f2bf(o1 - bf2f(h.y));
        l.z = f2bf(o2 - bf2f(h.z)); l.w = f2bf(o3 - bf2f(h.w));
        *reinterpret_cast<ushort4*>(&ol[(size_t)row * Dmod + tid * 4]) = l;
    }
}

// ---------------------------------------------------------------------------
// Split-bf16 MFMA GEMM, r13 PIPELINED (proven: -18us on o/down-proj).
// ---------------------------------------------------------------------------
template <int NKT, int ASPLIT, int BSPLIT, int RES>
__global__ __launch_bounds__(256, 2) void mfma_gemm_pipe(
    const u16* __restrict__ Ah, const u16* __restrict__ Al,
    const u16* __restrict__ Bh, const u16* __restrict__ Bl,
    const float* __restrict__ res, float* __restrict__ C,
    int M, int N)
{
    constexpr int Kd = NKT * 32;
    constexpr int NI = 4 + 2 * ASPLIT + 2 * BSPLIT; // issues/K-step
    static_assert((NKT - 2) % 3 == 0, "main loop unroll-3");

    __shared__ u16 AsH[3][128 * 32];                    // 24 KB
    __shared__ u16 BsH[3][128 * 32];                    // 24 KB
    __shared__ u16 AsL[ASPLIT ? 3 : 1][128 * 32];       // 24/8 KB
    __shared__ u16 BsL[BSPLIT ? 3 : 1][128 * 32];       // 24/8 KB

    const int tid = threadIdx.x;
    const int lane = tid & 63, wave = tid >> 6;
    const int wm = (wave >> 1) * 64, wn = (wave & 1) * 64;
    const int m0 = blockIdx.y * 128, n0 = blockIdx.x * 128;
    const int fm = lane & 15, quad = lane >> 4;
    const int fsw = (fm >> 1) & 3;
    const int fcol = (quad ^ fsw) * 8;

    f32x4 acc[4][4];
    #pragma unroll
    for (int i = 0; i < 4; ++i)
        #pragma unroll
        for (int j = 0; j < 4; ++j) acc[i][j] = (f32x4){0.f, 0.f, 0.f, 0.f};

    // staging: 256 thr * 16 B = 4 KB/issue; each 128x32 tile = 2 issues
    const int srow = tid >> 2;             // 0..63
    const int schk = tid & 3;
    const int sw   = schk ^ ((srow >> 1) & 3);   // f(srow+64)==f(srow)
    const u16* aS0 = &Ah[(size_t)(m0 + srow) * Kd + sw * 8];
    const u16* aS1 = &Ah[(size_t)(m0 + srow + 64) * Kd + sw * 8];
    const u16* bS0 = &Bh[(size_t)(n0 + srow) * Kd + sw * 8];
    const u16* bS1 = &Bh[(size_t)(n0 + srow + 64) * Kd + sw * 8];
    const u16* alS0 = ASPLIT ? &Al[(size_t)(m0 + srow) * Kd + sw * 8] : nullptr;
    const u16* alS1 = ASPLIT ? &Al[(size_t)(m0 + srow + 64) * Kd + sw * 8] : nullptr;
    const u16* blS0 = BSPLIT ? &Bl[(size_t)(n0 + srow) * Kd + sw * 8] : nullptr;
    const u16* blS1 = BSPLIT ? &Bl[(size_t)(n0 + srow + 64) * Kd + sw * 8] : nullptr;
    const int dst0 = srow * 32 + schk * 8;       // bytes = tid*16 (linear)
    const int dst1 = dst0 + 64 * 32;

#define PSTAGE(T, BUF) do {                                                  \
        async_copy16(aS0 + (T) * 32, &AsH[BUF][dst0]);                       \
        async_copy16(aS1 + (T) * 32, &AsH[BUF][dst1]);                       \
        if (ASPLIT) {                                                        \
            async_copy16(alS0 + (T) * 32, &AsL[BUF][dst0]);                  \
            async_copy16(alS1 + (T) * 32, &AsL[BUF][dst1]);                  \
        }                                                                    \
        async_copy16(bS0 + (T) * 32, &BsH[BUF][dst0]);                       \
        async_copy16(bS1 + (T) * 32, &BsH[BUF][dst1]);                       \
        if (BSPLIT) {                                                        \
            async_copy16(blS0 + (T) * 32, &BsL[BUF][dst0]);                  \
            async_copy16(blS1 + (T) * 32, &BsL[BUF][dst1]);                  \
        }                                                                    \
    } while (0)

// GATE: 1 = steady-state counted wait vmcnt(NI), 0 = drain, -1 = none.
#define PGATE(GATE) do {                                                     \
        if ((GATE) == 1) {                                                   \
            if constexpr (NI == 4)                                           \
                asm volatile("s_waitcnt vmcnt(4)" ::: "memory");             \
            else                                                             \
                asm volatile("s_waitcnt vmcnt(8)" ::: "memory");             \
        } else if ((GATE) == 0) {                                            \
            asm volatile("s_waitcnt vmcnt(0)" ::: "memory");                 \
        }                                                                    \
    } while (0)

#define PSTEP(BC, BN, T, PF, GATE) do {                                      \
    bf16x8 ah[4], bh[4], al[4], bl[4];                                       \
    _Pragma("unroll")                                                        \
    for (int t = 0; t < 4; ++t) {                                            \
        const int ra = (wm + t * 16 + fm) * 32 + fcol;                       \
        const int rb = (wn + t * 16 + fm) * 32 + fcol;                       \
        ah[t] = *reinterpret_cast<const bf16x8*>(&AsH[BC][ra]);              \
        bh[t] = *reinterpret_cast<const bf16x8*>(&BsH[BC][rb]);              \
        if (ASPLIT) al[t] = *reinterpret_cast<const bf16x8*>(&AsL[BC][ra]);  \
        if (BSPLIT) bl[t] = *reinterpret_cast<const bf16x8*>(&BsL[BC][rb]);  \
    }                                                                        \
    if (PF) PSTAGE((T) + 2, BN);                                             \
    __builtin_amdgcn_s_barrier();                                            \
    asm volatile("s_waitcnt lgkmcnt(0)" ::: "memory");                       \
    __builtin_amdgcn_sched_barrier(0);                                       \
    __builtin_amdgcn_s_setprio(1);                                           \
    _Pragma("unroll")                                                        \
    for (int mt = 0; mt < 4; ++mt)                                           \
        _Pragma("unroll")                                                    \
        for (int nt = 0; nt < 4; ++nt) {                                     \
            acc[mt][nt] = __builtin_amdgcn_mfma_f32_16x16x32_bf16(           \
                ah[mt], bh[nt], acc[mt][nt], 0, 0, 0);                       \
            if (BSPLIT)                                                      \
                acc[mt][nt] = __builtin_amdgcn_mfma_f32_16x16x32_bf16(       \
                    ah[mt], bl[nt], acc[mt][nt], 0, 0, 0);                   \
            if (ASPLIT)                                                      \
                acc[mt][nt] = __builtin_amdgcn_mfma_f32_16x16x32_bf16(       \
                    al[mt], bh[nt], acc[mt][nt], 0, 0, 0);                   \
        }                                                                    \
    __builtin_amdgcn_s_setprio(0);                                           \
    PGATE(GATE);                                                             \
    __builtin_amdgcn_s_barrier();                                            \
} while (0)

    // prologue: fill buffers 0 and 1 (2*NI in flight -> wait NI = buf0 done)
    PSTAGE(0, 0);
    PSTAGE(1, 1);
    PGATE(1);
    __builtin_amdgcn_s_barrier();

    #pragma unroll 1
    for (int t3 = 0; t3 < NKT - 2; t3 += 3) {
        PSTEP(0, 2, t3 + 0, true, 1);
        PSTEP(1, 0, t3 + 1, true, 1);
        PSTEP(2, 1, t3 + 2, true, 1);
    }
    // tail: t=NKT-2 (buf0, drain last loads), t=NKT-1 (buf1, nothing left)
    PSTEP(0, 2, NKT - 2, false, 0);
    PSTEP(1, 0, NKT - 1, false, -1);

#undef PSTEP
#undef PGATE
#undef PSTAGE

    const int cr = (lane >> 4) * 4, cn = lane & 15;
    #pragma unroll
    for (int mt = 0; mt < 4; ++mt)
        #pragma unroll
        for (int nt = 0; nt < 4; ++nt)
            #pragma unroll
            for (int r = 0; r < 4; ++r) {
                const int gm = m0 + wm + mt * 16 + cr + r;
                const int gn = n0 + wn + nt * 16 + cn;
                float v = acc[mt][nt][r];
                if (RES) v += res[(size_t)gm * N + gn];
                C[(size_t)gm * N + gn] = v;
            }
}

// ---------------------------------------------------------------------------
// Fused QKV GEMM + qk-norm + RoPE + bf16 split epilogue; V stored TRANSPOSED.
// r14: K-loop replaced with the r13-proven pipelined structure (triple
// buffer, counted vmcnt(4), setprio). MFMA order and epilogue unchanged.
// ---------------------------------------------------------------------------
__global__ __launch_bounds__(256, 2) void qkv_fused_kernel(
    const u16* __restrict__ Ah, const u16* __restrict__ Bh,
    const float* __restrict__ qn, const float* __restrict__ kn,
    const float* __restrict__ sinp, const float* __restrict__ cosp,
    u16* __restrict__ Qbh, u16* __restrict__ Qbl,
    u16* __restrict__ Kbh, u16* __restrict__ Kbl,
    u16* __restrict__ Vth, u16* __restrict__ Vtl)
{
    constexpr int Kd = 1024;
    constexpr int NKT = 32;
    __shared__ u16 As[3][128 * 32];    // 24 KB
    __shared__ u16 Bs[3][128 * 32];    // 24 KB -> 48 KB total, 2 blk/CU

    const int tid = threadIdx.x;
    const int lane = tid & 63, wave = tid >> 6;
    const int wm = (wave >> 1) * 64, wn = (wave & 1) * 64;
    const int m0 = blockIdx.y * 128, n0 = blockIdx.x * 128;
    const int fm = lane & 15, quad = lane >> 4;
    const int fsw = (fm >> 1) & 3;
    const int fcol = ((quad ^ fsw) * 8);

    f32x4 acc[4][4];
    #pragma unroll
    for (int i = 0; i < 4; ++i)
        #pragma unroll
        for (int j = 0; j < 4; ++j) acc[i][j] = (f32x4){0.f, 0.f, 0.f, 0.f};

    const int srow = tid >> 2;             // 0..63
    const int schk = tid & 3;
    const int sw   = schk ^ ((srow >> 1) & 3);
    const u16* aS0 = &Ah[(size_t)(m0 + srow) * Kd + sw * 8];
    const u16* aS1 = &Ah[(size_t)(m0 + srow + 64) * Kd + sw * 8];
    const u16* bS0 = &Bh[(size_t)(n0 + srow) * Kd + sw * 8];
    const u16* bS1 = &Bh[(size_t)(n0 + srow + 64) * Kd + sw * 8];
    const int dst0 = srow * 32 + schk * 8;
    const int dst1 = dst0 + 64 * 32;

#define QSTAGE(T, BUF) do {                                                  \
        async_copy16(aS0 + (T) * 32, &As[BUF][dst0]);                        \
        async_copy16(aS1 + (T) * 32, &As[BUF][dst1]);                        \
        async_copy16(bS0 + (T) * 32, &Bs[BUF][dst0]);                        \
        async_copy16(bS1 + (T) * 32, &Bs[BUF][dst1]);                        \
    } while (0)

#define QSTEP(BC, BN, T, PF, GATE) do {                                      \
    bf16x8 ah[4], bh[4];                                                     \
    _Pragma("unroll")                                                        \
    for (int t = 0; t < 4; ++t) {                                            \
        ah[t] = *reinterpret_cast<const bf16x8*>(                            \
            &As[BC][(wm + t * 16 + fm) * 32 + fcol]);                        \
        bh[t] = *reinterpret_cast<const bf16x8*>(                            \
            &Bs[BC][(wn + t * 16 + fm) * 32 + fcol]);                        \
    }                                                                        \
    if (PF) QSTAGE((T) + 2, BN);                                             \
    __builtin_amdgcn_s_barrier();                                            \
    asm volatile("s_waitcnt lgkmcnt(0)" ::: "memory");                       \
    __builtin_amdgcn_sched_barrier(0);                                       \
    __builtin_amdgcn_s_setprio(1);                                           \
    _Pragma("unroll")                                                        \
    for (int mt = 0; mt < 4; ++mt)                                           \
        _Pragma("unroll")                                                    \
        for (int nt = 0; nt < 4; ++nt)                                       \
            acc[mt][nt] = __builtin_amdgcn_mfma_f32_16x16x32_bf16(           \
                ah[mt], bh[nt], acc[mt][nt], 0, 0, 0);                       \
    __builtin_amdgcn_s_setprio(0);                                           \
    if ((GATE) == 1) {                                                       \
        asm volatile("s_waitcnt vmcnt(4)" ::: "memory");                     \
    } else if ((GATE) == 0) {                                                \
        asm volatile("s_waitcnt vmcnt(0)" ::: "memory");                     \
    }                                                                        \
    __builtin_amdgcn_s_barrier();                                            \
} while (0)

    QSTAGE(0, 0);
    QSTAGE(1, 1);
    asm volatile("s_waitcnt vmcnt(4)" ::: "memory");
    __builtin_amdgcn_s_barrier();

    #pragma unroll 1
    for (int t3 = 0; t3 < NKT - 2; t3 += 3) {
        QSTEP(0, 2, t3 + 0, true, 1);
        QSTEP(1, 0, t3 + 1, true, 1);
        QSTEP(2, 1, t3 + 2, true, 1);
    }
    QSTEP(0, 2, NKT - 2, false, 0);
    QSTEP(1, 0, NKT - 1, false, -1);

#undef QSTEP
#undef QSTAGE

    const int gn0 = n0 + wn;          // wave col base, 64-aligned
    const int l15 = lane & 15;

    if (gn0 < 1280) {
        // ---- Q or K: per-head RMSNorm + RoPE + split ----
        const bool isQ = (gn0 < 1024);
        const float* nsc = isQ ? qn : kn;
        const float osc = isQ ? 0.125f : 1.0f;
        u16* __restrict__ oh = isQ ? Qbh : Kbh;
        u16* __restrict__ ol = isQ ? Qbl : Kbl;
        const int rowstride = isQ ? 1024 : 256;
        const int colbase = isQ ? gn0 : gn0 - 1024;
        float sc[4];
        #pragma unroll
        for (int nt = 0; nt < 4; ++nt) sc[nt] = nsc[nt * 16 + l15];

        #pragma unroll
        for (int mt = 0; mt < 4; ++mt)
            #pragma unroll
            for (int r = 0; r < 4; ++r) {
                const int bt = m0 + wm + mt * 16 + quad * 4 + r;
                float v[4];
                #pragma unroll
                for (int nt = 0; nt < 4; ++nt) v[nt] = acc[mt][nt][r];
                float ss = v[0] * v[0] + v[1] * v[1] + v[2] * v[2] + v[3] * v[3];
                #pragma unroll
                for (int off = 1; off < 16; off <<= 1)
                    ss += __shfl_xor(ss, off, 16);
                const float rstd = rsqrtf(ss * (1.0f / 64.0f) + EPSF);
                float nv[4];
                #pragma unroll
                for (int nt = 0; nt < 4; ++nt) nv[nt] = v[nt] * rstd * sc[nt];
                const float s0 = sinp[bt * 32 + l15];
                const float c0 = cosp[bt * 32 + l15];
                const float s1 = sinp[bt * 32 + 16 + l15];
                const float c1 = cosp[bt * 32 + 16 + l15];
                float o[4];
                o[0] = (nv[0] * c0 - nv[2] * s0) * osc;
                o[1] = (nv[1] * c1 - nv[3] * s1) * osc;
                o[2] = (nv[2] * c0 + nv[0] * s0) * osc;
                o[3] = (nv[3] * c1 + nv[1] * s1) * osc;
                #pragma unroll
                for (int nt = 0; nt < 4; ++nt) {
                    const size_t off = (size_t)bt * rowstride + colbase + nt * 16 + l15;
                    const u16 hi = f2bf(o[nt]);
                    oh[off] = hi;
                    ol[off] = f2bf(o[nt] - bf2f(hi));
                }
            }
    } else {
        // ---- V: bf16 split, stored transposed: Vt[(b*4+g)*64+d][t] ----
        const int g = (gn0 - 1280) >> 6;
        const int b = (m0 + wm) >> 11;
        const int tb = ((m0 + wm) & 2047) + quad * 4;
        #pragma unroll
        for (int mt = 0; mt < 4; ++mt)
            #pragma unroll
            for (int nt = 0; nt < 4; ++nt) {
                const float v0 = acc[mt][nt][0], v1 = acc[mt][nt][1];
                const float v2 = acc[mt][nt][2], v3 = acc[mt][nt][3];
                ushort4 hv, lv;
                hv.x = f2bf(v0); hv.y = f2bf(v1); hv.z = f2bf(v2); hv.w = f2bf(v3);
                lv.x = f2bf(v0 - bf2f(hv.x)); lv.y = f2bf(v1 - bf2f(hv.y));
                lv.z = f2bf(v2 - bf2f(hv.z)); lv.w = f2bf(v3 - bf2f(hv.w));
                const size_t off =
                    ((size_t)((b * 4 + g) * 64 + nt * 16 + l15)) * Tseq + tb + mt * 16;
                *reinterpret_cast<ushort4*>(&Vth[off]) = hv;
                *reinterpret_cast<ushort4*>(&Vtl[off]) = lv;
            }
    }
}

// ---------------------------------------------------------------------------
// Fused gate/up GEMM, r14: r10 structure (4 phases/K-step, triple-buffer,
// counted vmcnt(6), setprio, conflict-free 16x16 reads) with the wave grid
// re-tiled (2 wave_m x 4 wave_n) -> (4 wave_m x 2 wave_n). Per-wave per
// K-step LDS reads drop 20 -> 16 b128 (A 16->8, B 4->8 but B-frags held in
// regs across the whole K-step) => 208 KB -> 176 KB LDS traffic (-15%),
// attacking the measured LDS-BW bound. Per-accumulator MFMA order (hi then
// lo) preserved -> bitwise-identical output.
// ---------------------------------------------------------------------------
#define GU_PHASE_SYNC()                                       \
    __builtin_amdgcn_s_barrier();                             \
    asm volatile("s_waitcnt lgkmcnt(0)" ::: "memory");        \
    __builtin_amdgcn_sched_barrier(0)

// 16 MFMA: 4 mf x {g,u} x 2 nf (NB0, NB0+1) with A-frag array AF.
#define GU_MFMA16(AF, NB0)                                                       \
    _Pragma("unroll")                                                            \
    for (int mf = 0; mf < 4; ++mf) {                                             \
        accg[mf][(NB0)] = __builtin_amdgcn_mfma_f32_16x16x32_bf16(               \
            AF[mf], bgf[(NB0)], accg[mf][(NB0)], 0, 0, 0);                       \
        accu[mf][(NB0)] = __builtin_amdgcn_mfma_f32_16x16x32_bf16(               \
            AF[mf], buf2[(NB0)], accu[mf][(NB0)], 0, 0, 0);                      \
        accg[mf][(NB0) + 1] = __builtin_amdgcn_mfma_f32_16x16x32_bf16(           \
            AF[mf], bgf[(NB0) + 1], accg[mf][(NB0) + 1], 0, 0, 0);               \
        accu[mf][(NB0) + 1] = __builtin_amdgcn_mfma_f32_16x16x32_bf16(           \
            AF[mf], buf2[(NB0) + 1], accu[mf][(NB0) + 1], 0, 0, 0);              \
    }

__global__ __launch_bounds__(512, 2) void gateup8_kernel(
    const u16* __restrict__ Yh, const u16* __restrict__ Yl,
    const u16* __restrict__ Gw, const u16* __restrict__ Uw,
    u16* __restrict__ FF)
{
    constexpr int NK = 32;                 // K=1024 / 32
    __shared__ u16 AsH[3][256 * 32];       // 48 KB
    __shared__ u16 AsL[3][256 * 32];       // 48 KB
    __shared__ u16 Gs[3][128 * 32];        // 24 KB
    __shared__ u16 Us[3][128 * 32];        // 24 KB  -> 144 KB total, 1 blk/CU

    const int tid  = threadIdx.x;
    const int lane = tid & 63;
    const int wave = tid >> 6;
    const int wave_m = wave >> 1;          // 0..3  -> A rows wave_m*64..+63
    const int wave_n = wave & 1;           // 0..1  -> B rows wave_n*64..+63

    // XCD-aware bijective swizzle: 512 wgs = 8 xcd * 64. Per XCD: 4 n-tiles
    // (gate+up panel 2 MB -> L2-resident), consecutive idx share the m-tile.
    const int wg  = blockIdx.x;
    const int xcd = wg & 7;
    const int idx = wg >> 3;               // 0..63
    const int ntile = xcd * 4 + (idx & 3); // 0..31
    const int mtile = idx >> 2;            // 0..15
    const int m0 = mtile * 256, n0 = ntile * 128;

    const int fm = lane & 15, quad = lane >> 4;
    const int fsw = (fm >> 1) & 3;
    const int fcol = (quad ^ fsw) * 8;

    f32x4 accg[4][4], accu[4][4];
    #pragma unroll
    for (int i = 0; i < 4; ++i)
        #pragma unroll
        for (int j = 0; j < 4; ++j) {
            accg[i][j] = (f32x4){0.f, 0.f, 0.f, 0.f};
            accu[i][j] = (f32x4){0.f, 0.f, 0.f, 0.f};
        }

    // ---- staging constants (512 thr * 16 B = 8 KB per issue) ----
    const int srow = tid >> 2;             // 0..127
    const int schk = tid & 3;
    const int sw   = schk ^ ((srow >> 1) & 3);   // same for srow+128 (128%4==0)
    const u16* aSrc0 = &Yh[(size_t)(m0 + srow) * 1024 + sw * 8];
    const u16* aSrc1 = &Yh[(size_t)(m0 + srow + 128) * 1024 + sw * 8];
    const u16* lSrc0 = &Yl[(size_t)(m0 + srow) * 1024 + sw * 8];
    const u16* lSrc1 = &Yl[(size_t)(m0 + srow + 128) * 1024 + sw * 8];
    const u16* gSrc  = &Gw[(size_t)(n0 + srow) * 1024 + sw * 8];
    const u16* uSrc  = &Uw[(size_t)(n0 + srow) * 1024 + sw * 8];
    const int aDst0 = srow * 32 + schk * 8;      // bytes = tid*16 (linear)
    const int aDst1 = aDst0 + 128 * 32;

#define STAGE_AH(T, BUF) do {                                  \
        async_copy16(aSrc0 + (T) * 32, &AsH[BUF][aDst0]);      \
        async_copy16(aSrc1 + (T) * 32, &AsH[BUF][aDst1]); } while (0)
#define STAGE_AL(T, BUF) do {                                  \
        async_copy16(lSrc0 + (T) * 32, &AsL[BUF][aDst0]);      \
        async_copy16(lSrc1 + (T) * 32, &AsL[BUF][aDst1]); } while (0)
#define STAGE_B(T, BUF) do {                                   \
        async_copy16(gSrc + (T) * 32, &Gs[BUF][aDst0]);        \
        async_copy16(uSrc + (T) * 32, &Us[BUF][aDst0]); } while (0)

    // ---- fragment read offsets (u16 units) ----
    int raOff[4], rbOff[4];
    #pragma unroll
    for (int mf = 0; mf < 4; ++mf)
        raOff[mf] = (wave_m * 64 + mf * 16 + fm) * 32 + fcol;
    #pragma unroll
    for (int nf = 0; nf < 4; ++nf)
        rbOff[nf] = (wave_n * 64 + nf * 16 + fm) * 32 + fcol;

    // ---- prologue: fill buffers 0 and 1 (12 loads in flight -> wait 6) ----
    STAGE_AH(0, 0); STAGE_AL(0, 0); STAGE_B(0, 0);
    STAGE_AH(1, 1); STAGE_AL(1, 1); STAGE_B(1, 1);
    asm volatile("s_waitcnt vmcnt(6)" ::: "memory");
    __builtin_amdgcn_s_barrier();

    int bcur = 0, bnxt = 2;
    #pragma unroll 1
    for (int t = 0; t < NK; ++t) {
        const bool pf = (t + 2 < NK);
        bf16x8 bgf[4], buf2[4];        // all B frags, held across the K-step
        bf16x8 ahf[4];                 // A-hi frags, held across ph0-ph1

        // ---- phase 0: read all B frags + A-hi; 16 MFMA (hi x nf0-1) ----
        {
            #pragma unroll
            for (int nf = 0; nf < 4; ++nf) {
                bgf[nf]  = *reinterpret_cast<const bf16x8*>(&Gs[bcur][rbOff[nf]]);
                buf2[nf] = *reinterpret_cast<const bf16x8*>(&Us[bcur][rbOff[nf]]);
            }
            #pragma unroll
            for (int mf = 0; mf < 4; ++mf)
                ahf[mf] = *reinterpret_cast<const bf16x8*>(&AsH[bcur][raOff[mf]]);
            if (pf) STAGE_AH(t + 2, bnxt);
            GU_PHASE_SYNC();
            __builtin_amdgcn_s_setprio(1);
            GU_MFMA16(ahf, 0);
            __builtin_amdgcn_s_setprio(0);
            __builtin_amdgcn_s_barrier();
        }
        // ---- phase 1: 16 MFMA (hi x nf2-3); stage A-lo(t+2) ----
        {
            if (pf) STAGE_AL(t + 2, bnxt);
            GU_PHASE_SYNC();
            __builtin_amdgcn_s_setprio(1);
            GU_MFMA16(ahf, 2);
            __builtin_amdgcn_s_setprio(0);
            __builtin_amdgcn_s_barrier();
        }
        bf16x8 alf[4];                 // A-lo frags, held across ph2-ph3
        // ---- phase 2: read A-lo; 16 MFMA (lo x nf0-1); stage B(t+2) ----
        {
            #pragma unroll
            for (int mf = 0; mf < 4; ++mf)
                alf[mf] = *reinterpret_cast<const bf16x8*>(&AsL[bcur][raOff[mf]]);
            if (pf) STAGE_B(t + 2, bnxt);
            GU_PHASE_SYNC();
            __builtin_amdgcn_s_setprio(1);
            GU_MFMA16(alf, 0);
            __builtin_amdgcn_s_setprio(0);
            __builtin_amdgcn_s_barrier();
        }
        // ---- phase 3: 16 MFMA (lo x nf2-3); counted vmcnt ----
        {
            GU_PHASE_SYNC();
            __builtin_amdgcn_s_setprio(1);
            GU_MFMA16(alf, 2);
            __builtin_amdgcn_s_setprio(0);
            if (t + 2 < NK) {
                asm volatile("s_waitcnt vmcnt(6)" ::: "memory");
            } else if (t + 1 < NK) {
                asm volatile("s_waitcnt vmcnt(0)" ::: "memory");
            }
            __builtin_amdgcn_s_barrier();
        }

        bcur = (bcur == 2) ? 0 : bcur + 1;
        bnxt = (bnxt == 2) ? 0 : bnxt + 1;
    }
#undef STAGE_AH
#undef STAGE_AL
#undef STAGE_B

    // ---- epilogue: silu(g)*u -> bf16 ----
    const int cr = quad * 4;
    #pragma unroll
    for (int mf = 0; mf < 4; ++mf)
        #pragma unroll
        for (int nf = 0; nf < 4; ++nf)
            #pragma unroll
            for (int r = 0; r < 4; ++r) {
                const int gm = m0 + wave_m * 64 + mf * 16 + cr + r;
                const int gn = n0 + wave_n * 64 + nf * 16 + fm;
                const float g = accg[mf][nf][r];
                const float ff = (g / (1.0f + __expf(-g))) * accu[mf][nf][r];
                FF[(size_t)gm * Ff + gn] = f2bf(ff);
            }
}

// ---------------------------------------------------------------------------
// MFMA flash attention v3 (EXACT r8 revert — one 16-row window per block).
// ---------------------------------------------------------------------------
__global__ __launch_bounds__(256) void attn_mfma_kernel(
    const u16* __restrict__ Qh, const u16* __restrict__ Ql,
    const u16* __restrict__ Kh, const u16* __restrict__ Kl,
    const u16* __restrict__ Vth, const u16* __restrict__ Vtl,
    u16* __restrict__ AOh, u16* __restrict__ AOl)
{
    __shared__ u16 KsH[64 * 72];
    __shared__ u16 KsL[64 * 72];
    __shared__ u16 VsH[64 * 72];
    __shared__ u16 VsL[64 * 72];
    __shared__ u16 Ps[4][16 * 72];

    const int tid = threadIdx.x;
    const int wave = tid >> 6, lane = tid & 63;
    const int l15 = lane & 15, quad = lane >> 4;

    const int bg = blockIdx.x & 7;
    const int b = bg >> 2, g = bg & 3;
    const int win = 127 - (blockIdx.x >> 3);
    const int t0 = win * 16;
    const int h = g * 4 + wave;

    bf16x8 qh[2], ql[2];
    {
        const size_t qrow = (size_t)(b * Tseq + t0 + l15) * 1024 + h * 64;
        #pragma unroll
        for (int ks = 0; ks < 2; ++ks) {
            qh[ks] = *reinterpret_cast<const bf16x8*>(&Qh[qrow + ks * 32 + quad * 8]);
            ql[ks] = *reinterpret_cast<const bf16x8*>(&Ql[qrow + ks * 32 + quad * 8]);
        }
    }

    const int srow = tid >> 2;
    const int scol = (tid & 3) * 16;
    const size_t kgb = (size_t)(b * Tseq) * 256 + g * 64 + scol;
    const size_t vgb = (size_t)(bg * 64 + srow) * Tseq + scol;

    const int nit = t0 / 64 + 1;

    uint4 ck0, ck1, cl0, cl1, cv0, cv1, cw0, cw1;
    {
        const size_t ka = kgb + (size_t)srow * 256;
        ck0 = *reinterpret_cast<const uint4*>(&Kh[ka]);
        ck1 = *reinterpret_cast<const uint4*>(&Kh[ka + 8]);
        cl0 = *reinterpret_cast<const uint4*>(&Kl[ka]);
        cl1 = *reinterpret_cast<const uint4*>(&Kl[ka + 8]);
        cv0 = *reinterpret_cast<const uint4*>(&Vth[vgb]);
        cv1 = *reinterpret_cast<const uint4*>(&Vth[vgb + 8]);
        cw0 = *reinterpret_cast<const uint4*>(&Vtl[vgb]);
        cw1 = *reinterpret_cast<const uint4*>(&Vtl[vgb + 8]);
    }

    f32x4 oacc[4];
    #pragma unroll
    for (int nt = 0; nt < 4; ++nt) oacc[nt] = (f32x4){0.f, 0.f, 0.f, 0.f};
    float m_r[4], l_r[4];
    #pragma unroll
    for (int r = 0; r < 4; ++r) { m_r[r] = -1e30f; l_r[r] = 0.0f; }

    u16* psw = &Ps[wave][0];
    const int lb = srow * 72 + scol;

    for (int it = 0; it < nit; ++it) {
        const int s0 = it * 64;
        const bool diag = (it == nit - 1);

        __syncthreads();
        *reinterpret_cast<uint4*>(&KsH[lb])     = ck0;
        *reinterpret_cast<uint4*>(&KsH[lb + 8]) = ck1;
        *reinterpret_cast<uint4*>(&KsL[lb])     = cl0;
        *reinterpret_cast<uint4*>(&KsL[lb + 8]) = cl1;
        *reinterpret_cast<uint4*>(&VsH[lb])     = cv0;
        *reinterpret_cast<uint4*>(&VsH[lb + 8]) = cv1;
        *reinterpret_cast<uint4*>(&VsL[lb])     = cw0;
        *reinterpret_cast<uint4*>(&VsL[lb + 8]) = cw1;
        if (it + 1 < nit) {
            const size_t ka = kgb + (size_t)(s0 + 64 + srow) * 256;
            ck0 = *reinterpret_cast<const uint4*>(&Kh[ka]);
            ck1 = *reinterpret_cast<const uint4*>(&Kh[ka + 8]);
            cl0 = *reinterpret_cast<const uint4*>(&Kl[ka]);
            cl1 = *reinterpret_cast<const uint4*>(&Kl[ka + 8]);
            const size_t va = vgb + s0 + 64;
            cv0 = *reinterpret_cast<const uint4*>(&Vth[va]);
            cv1 = *reinterpret_cast<const uint4*>(&Vth[va + 8]);
            cw0 = *reinterpret_cast<const uint4*>(&Vtl[va]);
            cw1 = *reinterpret_cast<const uint4*>(&Vtl[va + 8]);
        }
        __syncthreads();

        f32x4 sacc[4];
        #pragma unroll
        for (int nt = 0; nt < 4; ++nt) sacc[nt] = (f32x4){0.f, 0.f, 0.f, 0.f};

        #pragma unroll
        for (int ks = 0; ks < 2; ++ks) {
            bf16x8 kfh[4], kfl[4];
            #pragma unroll
            for (int nt = 0; nt < 4; ++nt) {
                const int a = (nt * 16 + l15) * 72 + ks * 32 + quad * 8;
                kfh[nt] = *reinterpret_cast<const bf16x8*>(&KsH[a]);
                kfl[nt] = *reinterpret_cast<const bf16x8*>(&KsL[a]);
            }
            #pragma unroll
            for (int nt = 0; nt < 4; ++nt) {
                sacc[nt] = __builtin_amdgcn_mfma_f32_16x16x32_bf16(qh[ks], kfh[nt], sacc[nt], 0, 0, 0);
                sacc[nt] = __builtin_amdgcn_mfma_f32_16x16x32_bf16(ql[ks], kfh[nt], sacc[nt], 0, 0, 0);
                sacc[nt] = __builtin_amdgcn_mfma_f32_16x16x32_bf16(qh[ks], kfl[nt], sacc[nt], 0, 0, 0);
            }
        }

        if (diag) {
            #pragma unroll
            for (int nt = 0; nt < 4; ++nt) {
                const int sg = s0 + nt * 16 + l15;
                #pragma unroll
                for (int r = 0; r < 4; ++r)
                    if (sg > t0 + quad * 4 + r) sacc[nt][r] = -1e30f;
            }
        }

        #pragma unroll
        for (int r = 0; r < 4; ++r) {
            float mx = fmaxf(fmaxf(sacc[0][r], sacc[1][r]),
                             fmaxf(sacc[2][r], sacc[3][r]));
            #pragma unroll
            for (int off = 1; off < 16; off <<= 1)
                mx = fmaxf(mx, __shfl_xor(mx, off, 16));
            const float mnew = fmaxf(m_r[r], mx);
            const float alpha = __expf(m_r[r] - mnew);
            m_r[r] = mnew;

            float rs = 0.0f;
            #pragma unroll
            for (int nt = 0; nt < 4; ++nt) {
                const float p = __expf(sacc[nt][r] - mnew);
                sacc[nt][r] = p;
                rs += p;
            }
            #pragma unroll
            for (int off = 1; off < 16; off <<= 1)
                rs += __shfl_xor(rs, off, 16);
            l_r[r] = l_r[r] * alpha + rs;
            #pragma unroll
            for (int nt = 0; nt < 4; ++nt) oacc[nt][r] *= alpha;
            #pragma unroll
            for (int nt = 0; nt < 4; ++nt)
                psw[(quad * 4 + r) * 72 + nt * 16 + l15] = f2bf(sacc[nt][r]);
        }

        #pragma unroll
        for (int ks = 0; ks < 2; ++ks) {
            const bf16x8 pa = *reinterpret_cast<const bf16x8*>(
                &psw[l15 * 72 + ks * 32 + quad * 8]);
            bf16x8 vfh[4], vfl[4];
            #pragma unroll
            for (int nt = 0; nt < 4; ++nt) {
                const int a = (nt * 16 + l15) * 72 + ks * 32 + quad * 8;
                vfh[nt] = *reinterpret_cast<const bf16x8*>(&VsH[a]);
                vfl[nt] = *reinterpret_cast<const bf16x8*>(&VsL[a]);
            }
            #pragma unroll
            for (int nt = 0; nt < 4; ++nt) {
                oacc[nt] = __builtin_amdgcn_mfma_f32_16x16x32_bf16(pa, vfh[nt], oacc[nt], 0, 0, 0);
                oacc[nt] = __builtin_amdgcn_mfma_f32_16x16x32_bf16(pa, vfl[nt], oacc[nt], 0, 0, 0);
            }
        }
    }

    #pragma unroll
    for (int r = 0; r < 4; ++r) {
        const float inv = 1.0f / l_r[r];
        const size_t orow = (size_t)(b * Tseq + t0 + quad * 4 + r) * 1024 + h * 64;
        #pragma unroll
        for (int nt = 0; nt < 4; ++nt) {
            const float o = oacc[nt][r] * inv;
            const u16 hi = f2bf(o);
            AOh[orow + nt * 16 + l15] = hi;
            AOl[orow + nt * 16 + l15] = f2bf(o - bf2f(hi));
        }
    }
}

// ---------------------------------------------------------------------------
// Host launcher
// ---------------------------------------------------------------------------
extern "C" void kernel_launch(void* const* d_in, const int* in_sizes, int n_in,
                              void* d_out, int out_size, void* d_ws,
                              size_t ws_size, hipStream_t stream)
{
    const float* hidden = (const float*)d_in[0];
    const float* sinp   = (const float*)d_in[1];
    const float* cosp   = (const float*)d_in[2];
    // d_in[3] = mask — causal, handled analytically
    const float* ln1    = (const float*)d_in[4];
    const float* ln2    = (const float*)d_in[5];
    const float* qn     = (const float*)d_in[6];
    const float* kn     = (const float*)d_in[7];
    const float* q_w    = (const float*)d_in[8];
    const float* k_w    = (const float*)d_in[9];
    const float* v_w    = (const float*)d_in[10];
    const float* o_w    = (const float*)d_in[11];
    const float* gate_w = (const float*)d_in[12];
    const float* up_w   = (const float*)d_in[13];
    const float* down_w = (const float*)d_in[14];
    float* out = (float*)d_out;

    // ---- workspace layout (116.4 MB; capacity >= 120.6 MB proven r8) ----
    char* base = (char*)d_ws;
    u16*   OTh  = (u16*)(base);                //  2 MB
    u16*   OTl  = (u16*)(base + 2097152);      //  2 MB
    u16*   GTh  = (u16*)(base + 4194304);      //  8 MB
    u16*   UTh  = (u16*)(base + 12582912);     //  8 MB
    u16*   DTh  = (u16*)(base + 20971520);     //  8 MB
    u16*   QKVT = (u16*)(base + 29360128);     //  3 MB
    u16*   Xh   = (u16*)(base + 32505856);     //  8 MB
    u16*   Qbh  = (u16*)(base + 40894464);     //  8 MB
    u16*   Qbl  = (u16*)(base + 49283072);     //  8 MB
    u16*   Kbh  = (u16*)(base + 57671680);     //  2 MB
    u16*   Kbl  = (u16*)(base + 59768832);     //  2 MB
    u16*   Vth  = (u16*)(base + 61865984);     //  2 MB
    u16*   Vtl  = (u16*)(base + 63963136);     //  2 MB
    u16*   AOh  = (u16*)(base + 66060288);     //  8 MB
    u16*   AOl  = (u16*)(base + 74448896);     //  8 MB
    u16*   FFh  = (u16*)(base + 82837504);     // 32 MB (end 116,391,936)

    // aliases (lifetime-checked):
    float* H2 = (float*)Qbh;   // 16 MB over Qbh+Qbl (Q dead post-attn)
    u16*   Yh = Kbh;           //  8 MB over Kbh..Vtl (K/V dead post-attn)
    u16*   Yl = AOh;           //  8 MB over AOh (AO dead post-o-proj)

    // 0. all weight prep, one launch
    wprep_all_kernel<<<14848, 256, 0, stream>>>(
        q_w, k_w, v_w, o_w, gate_w, up_w, down_w,
        QKVT, OTh, OTl, GTh, UTh, DTh);

    // 1. x = rmsnorm(hidden, ln1) -> bf16
    rmsnorm_split_kernel<0><<<Mrows, 256, 0, stream>>>(hidden, ln1, Xh, nullptr);

    // 2. fused qkv projection + qknorm + rope + split + V-transpose (r14 pipe)
    qkv_fused_kernel<<<dim3(12, 32), 256, 0, stream>>>(
        Xh, QKVT, qn, kn, sinp, cosp, Qbh, Qbl, Kbh, Kbl, Vth, Vtl);

    // 3. MFMA flash attention v3 (r8 revert) -> AO bf16 hi/lo
    attn_mfma_kernel<<<Bsz * Gg * (Tseq / 16), 256, 0, stream>>>(
        Qbh, Qbl, Kbh, Kbl, Vth, Vtl, AOh, AOl);

    // 4. hidden2 = hidden + attn @ o_w  (split x split) — r13 pipelined
    mfma_gemm_pipe<32, 1, 1, 1><<<dim3(8, 32), 256, 0, stream>>>(
        AOh, AOl, OTh, OTl, hidden, H2, Mrows, Dmod);

    // 5. y = rmsnorm(hidden2, ln2) -> bf16 hi/lo
    rmsnorm_split_kernel<1><<<Mrows, 256, 0, stream>>>(H2, ln2, Yh, Yl);

    // 6. ff = silu(y@gate_w) * (y@up_w) -> FF bf16 (r14: 4x2 wave tiling,
    //    -15% LDS traffic; phase/sync structure and numerics unchanged)
    gateup8_kernel<<<512, 512, 0, stream>>>(Yh, Yl, GTh, UTh, FFh);

    // 7. out = hidden2 + ff @ down_w — r13 pipelined
    mfma_gemm_pipe<128, 0, 0, 1><<<dim3(8, 32), 256, 0, stream>>>(
        FFh, nullptr, DTh, nullptr, H2, out, Mrows, Dmod);
}